// Round 1
// baseline (2001.410 us; speedup 1.0000x reference)
//
#include <hip/hip_runtime.h>
#include <math.h>

typedef unsigned long long U64;

// ---------------------------------------------------------------------------
// Constants (match reference generate_anchors; precomputed f32-exact)
// base anchor half-width/half-height, anchor a = ratio_idx*3 + scale_idx
// ratios {0.5,1,2}, scales {128,256,512}
// ---------------------------------------------------------------------------
__device__ const float g_bw[9] = {91.f, 181.f, 362.f, 64.f, 128.f, 256.f, 45.f, 91.f, 181.f};
__device__ const float g_bh[9] = {45.f, 91.f, 181.f, 64.f, 128.f, 256.f, 91.f, 181.f, 362.f};

// ---------------------------------------------------------------------------
// K1: transpose w_conv (512 x 4608, o-major) -> wmat (4608 x 512, k-major)
// ---------------------------------------------------------------------------
__global__ __launch_bounds__(256) void k_transpose_w(const float* __restrict__ w_conv,
                                                     float* __restrict__ wmat) {
    __shared__ float tile[32][33];
    int k0 = blockIdx.x * 32, o0 = blockIdx.y * 32;
    int tx = threadIdx.x & 31, tgy = threadIdx.x >> 5;  // 32 x 8
    for (int r = tgy; r < 32; r += 8)
        tile[r][tx] = w_conv[(size_t)(o0 + r) * 4608 + k0 + tx];
    __syncthreads();
    for (int r = tgy; r < 32; r += 8)
        wmat[(size_t)(k0 + r) * 512 + o0 + tx] = tile[tx][r];
}

// ---------------------------------------------------------------------------
// K2: 3x3 conv 512->512 SAME + bias + relu, as implicit GEMM.
// M=16384 pixels (b,h,w), N=512 outch, K=4608 (c*9+ry*3+rx).
// Block tile 128x128, 256 threads, 8x8 per-thread, BK=16.
// Output feat is NHWC: feat[pixel][outch].
// ---------------------------------------------------------------------------
#define CBK 16
__global__ __launch_bounds__(256) void k_conv3(const float* __restrict__ fm,
                                               const float* __restrict__ wmat,
                                               const float* __restrict__ bconv,
                                               float* __restrict__ feat) {
    __shared__ float As[CBK][128];
    __shared__ float Bs[CBK][128];
    int t = threadIdx.x;
    int p0 = blockIdx.x * 128, o0 = blockIdx.y * 128;
    int tx = t & 15, ty = t >> 4;
    int scol = t & 127, srow = t >> 7;  // staging: col 0..127, row parity 0/1
    int P = p0 + scol;
    int bb = P >> 12, hh = (P >> 6) & 63, wwp = P & 63;
    const float* fmb = fm + ((size_t)bb << 12) * 512;

    float acc[8][8];
#pragma unroll
    for (int i2 = 0; i2 < 8; ++i2)
#pragma unroll
        for (int j2 = 0; j2 < 8; ++j2) acc[i2][j2] = 0.f;

    for (int k0 = 0; k0 < 4608; k0 += CBK) {
#pragma unroll
        for (int i2 = 0; i2 < 8; ++i2) {
            int kk = srow + i2 * 2;
            int k = k0 + kk;
            int c = k / 9;             // compiler magic-div
            int r9 = k - c * 9;
            int ry = (r9 * 11) >> 5;   // r9/3 for r9 in [0,9)
            int rx = r9 - ry * 3;
            int h2 = hh + ry - 1, w2 = wwp + rx - 1;
            float v = 0.f;
            if (((unsigned)h2 < 64u) && ((unsigned)w2 < 64u))
                v = fmb[((size_t)c << 12) + (h2 << 6) + w2];
            As[kk][scol] = v;
            Bs[kk][scol] = wmat[(size_t)k * 512 + o0 + scol];
        }
        __syncthreads();
#pragma unroll
        for (int kk = 0; kk < CBK; ++kk) {
            float4 a0 = *(const float4*)&As[kk][tx * 4];
            float4 a1 = *(const float4*)&As[kk][64 + tx * 4];
            float4 b0 = *(const float4*)&Bs[kk][ty * 4];
            float4 b1 = *(const float4*)&Bs[kk][64 + ty * 4];
            float av[8] = {a0.x, a0.y, a0.z, a0.w, a1.x, a1.y, a1.z, a1.w};
            float bv[8] = {b0.x, b0.y, b0.z, b0.w, b1.x, b1.y, b1.z, b1.w};
#pragma unroll
            for (int i2 = 0; i2 < 8; ++i2)
#pragma unroll
                for (int j2 = 0; j2 < 8; ++j2) acc[i2][j2] += av[i2] * bv[j2];
        }
        __syncthreads();
    }
    // epilogue: bias + relu + store NHWC
    float4 bc0, bc1;
    bc0.x = bconv[o0 + 4 * ty + 0]; bc0.y = bconv[o0 + 4 * ty + 1];
    bc0.z = bconv[o0 + 4 * ty + 2]; bc0.w = bconv[o0 + 4 * ty + 3];
    bc1.x = bconv[o0 + 64 + 4 * ty + 0]; bc1.y = bconv[o0 + 64 + 4 * ty + 1];
    bc1.z = bconv[o0 + 64 + 4 * ty + 2]; bc1.w = bconv[o0 + 64 + 4 * ty + 3];
#pragma unroll
    for (int i2 = 0; i2 < 8; ++i2) {
        int P2 = p0 + ((i2 < 4) ? (4 * tx + i2) : (64 + 4 * tx + (i2 - 4)));
        float* fo = feat + (size_t)P2 * 512 + o0;
        float4 v0, v1;
        v0.x = fmaxf(acc[i2][0] + bc0.x, 0.f); v0.y = fmaxf(acc[i2][1] + bc0.y, 0.f);
        v0.z = fmaxf(acc[i2][2] + bc0.z, 0.f); v0.w = fmaxf(acc[i2][3] + bc0.w, 0.f);
        v1.x = fmaxf(acc[i2][4] + bc1.x, 0.f); v1.y = fmaxf(acc[i2][5] + bc1.y, 0.f);
        v1.z = fmaxf(acc[i2][6] + bc1.z, 0.f); v1.w = fmaxf(acc[i2][7] + bc1.w, 0.f);
        *(float4*)(fo + 4 * ty) = v0;
        *(float4*)(fo + 64 + 4 * ty) = v1;
    }
}

// ---------------------------------------------------------------------------
// K3: 1x1 heads. Each thread = one pixel, computes all 45 dots (9 cls + 36 box).
// Weights read via wave-uniform addresses -> scalar loads (L2-resident, 92 KB).
// Writes sigmoid scores (B,N) and raw deltas (B,N,4).
// ---------------------------------------------------------------------------
__global__ __launch_bounds__(256) void k_heads(const float* __restrict__ feat,
                                               const float* __restrict__ w_cls,
                                               const float* __restrict__ b_cls,
                                               const float* __restrict__ w_box,
                                               const float* __restrict__ b_box,
                                               float* __restrict__ scores,
                                               float* __restrict__ deltas) {
    int p = blockIdx.x * 256 + threadIdx.x;  // 0..16383
    int b = p >> 12, pixloc = p & 4095;
    const float* fr = feat + (size_t)p * 512;
    float acc[45];
#pragma unroll
    for (int o = 0; o < 45; ++o) acc[o] = 0.f;
    for (int c = 0; c < 512; c += 4) {
        float4 f = *(const float4*)(fr + c);
#pragma unroll
        for (int o = 0; o < 45; ++o) {
            const float* wr = (o < 9) ? (w_cls + o * 512 + c) : (w_box + (o - 9) * 512 + c);
            acc[o] += f.x * wr[0] + f.y * wr[1] + f.z * wr[2] + f.w * wr[3];
        }
    }
    int sbase = b * 36864 + pixloc * 9;
#pragma unroll
    for (int o = 0; o < 9; ++o) {
        float x = acc[o] + b_cls[o];
        scores[sbase + o] = 1.f / (1.f + expf(-x));
    }
#pragma unroll
    for (int c36 = 0; c36 < 36; ++c36) {
        float x = acc[9 + c36] + b_box[c36];
        int a = c36 >> 2, comp = c36 & 3;
        deltas[(size_t)(sbase + a) * 4 + comp] = x;
    }
}

// ---------------------------------------------------------------------------
// K4: decode proposals + build sort keys.
// key = (score_bits ^ 0x80000000)<<32 | ~index  -> descending sort gives
// (score desc, index asc) = lax.top_k stable order. Pad [36864,65536) with 0.
// ---------------------------------------------------------------------------
__global__ __launch_bounds__(256) void k_decode_keys(const float* __restrict__ scores,
                                                     const float* __restrict__ deltas,
                                                     U64* __restrict__ keys,
                                                     float4* __restrict__ proposals) {
    int g = blockIdx.x * 256 + threadIdx.x;  // 0..262143
    int b = g >> 16, i = g & 65535;
    if (i < 36864) {
        float s = scores[b * 36864 + i];
        keys[g] = (((U64)(__float_as_uint(s) ^ 0x80000000u)) << 32) | (unsigned)(~(unsigned)i);
        int pix = i / 9;
        int a = i - pix * 9;
        int h = pix >> 6, w = pix & 63;
        float bw = g_bw[a], bh = g_bh[a];
        float cxa = (float)(w * 16), cya = (float)(h * 16);  // exact (symmetric base)
        float wa = 2.f * bw, ha = 2.f * bh;
        const float4 d = *(const float4*)(deltas + (size_t)(b * 36864 + i) * 4);
        float dw = fminf(d.z, 4.135166556742356f);  // log(1000/16)
        float dh = fminf(d.w, 4.135166556742356f);
        float cx = d.x * wa + cxa;
        float cy = d.y * ha + cya;
        float pw = expf(dw) * wa;
        float ph = expf(dh) * ha;
        proposals[b * 36864 + i] =
            make_float4(cx - 0.5f * pw, cy - 0.5f * ph, cx + 0.5f * pw, cy + 0.5f * ph);
    } else {
        keys[g] = 0ull;
    }
}

// ---------------------------------------------------------------------------
// Bitonic sort, descending, 4 independent chunks of 65536 u64 keys.
// ---------------------------------------------------------------------------
__device__ inline void cmp_stage(U64* s, int j, int k, int ibase, int tid) {
    for (int p = tid; p < 1024; p += 256) {
        int il = ((p & ~(j - 1)) << 1) | (p & (j - 1));
        int ip = il | j;
        int ib = ibase + il;
        U64 a = s[il], c = s[ip];
        bool desc = ((ib & k) == 0);
        bool sw = desc ? (a < c) : (a > c);
        if (sw) { s[il] = c; s[ip] = a; }
    }
}

__global__ __launch_bounds__(256) void k_sort_local(U64* __restrict__ keys, int kstart) {
    __shared__ U64 s[2048];
    int tid = threadIdx.x;
    size_t base = (size_t)blockIdx.x * 2048;
    int ibase = (int)(base & 65535u);  // within-batch index base
    for (int e = tid; e < 2048; e += 256) s[e] = keys[base + e];
    __syncthreads();
    if (kstart == 0) {
        for (int k = 2; k <= 2048; k <<= 1)
            for (int j = k >> 1; j >= 1; j >>= 1) {
                cmp_stage(s, j, k, ibase, tid);
                __syncthreads();
            }
    } else {
        for (int j = 1024; j >= 1; j >>= 1) {
            cmp_stage(s, j, kstart, ibase, tid);
            __syncthreads();
        }
    }
    for (int e = tid; e < 2048; e += 256) keys[base + e] = s[e];
}

__global__ __launch_bounds__(256) void k_sort_global(U64* __restrict__ keys, int k, int j) {
    int t = blockIdx.x * 256 + threadIdx.x;  // 131072 pairs
    int il = ((t & ~(j - 1)) << 1) | (t & (j - 1));
    int ip = il | j;
    bool desc = (((il & 65535) & k) == 0);
    U64 a = keys[il], c = keys[ip];
    bool sw = desc ? (a < c) : (a > c);
    if (sw) { keys[il] = c; keys[ip] = a; }
}

// ---------------------------------------------------------------------------
// K6: gather top-2000 per batch, clip to image, min-size filter.
// ---------------------------------------------------------------------------
__global__ __launch_bounds__(256) void k_topk_gather(const U64* __restrict__ keys,
                                                     const float4* __restrict__ proposals,
                                                     float4* __restrict__ tb_boxes,
                                                     float* __restrict__ tb_scores) {
    int g = blockIdx.x * 256 + threadIdx.x;
    if (g >= 8000) return;
    int b = g / 2000, r = g - b * 2000;
    U64 key = keys[b * 65536 + r];
    unsigned n = ~((unsigned)key);
    float s = __uint_as_float(((unsigned)(key >> 32)) ^ 0x80000000u);
    float4 p = proposals[b * 36864 + (int)n];
    float x1 = fminf(fmaxf(p.x, 0.f), 1024.f);
    float y1 = fminf(fmaxf(p.y, 0.f), 1024.f);
    float x2 = fminf(fmaxf(p.z, 0.f), 1024.f);
    float y2 = fminf(fmaxf(p.w, 0.f), 1024.f);
    bool small_ = ((x2 - x1) < 16.f) || ((y2 - y1) < 16.f);
    tb_boxes[g] = make_float4(x1, y1, x2, y2);
    tb_scores[g] = small_ ? -INFINITY : s;
}

// ---------------------------------------------------------------------------
// K7: NMS suppression bitmask. mask[b][i][jt] bit jj = (j>i && iou>0.7).
// ---------------------------------------------------------------------------
__global__ __launch_bounds__(64) void k_nms_mask(const float4* __restrict__ tb_boxes,
                                                 U64* __restrict__ mask) {
    int jt = blockIdx.x, it = blockIdx.y, b = blockIdx.z;
    int tid = threadIdx.x;
    __shared__ float4 jb[64];
    int j0 = jt * 64;
    {
        int j = j0 + tid;
        jb[tid] = (j < 2000) ? tb_boxes[b * 2000 + j] : make_float4(0.f, 0.f, 0.f, 0.f);
    }
    __syncthreads();
    int i = it * 64 + tid;
    if (i >= 2000) return;
    float4 bi = tb_boxes[b * 2000 + i];
    float ai = (bi.z - bi.x) * (bi.w - bi.y);
    U64 bits = 0;
#pragma unroll 4
    for (int jj = 0; jj < 64; ++jj) {
        int j = j0 + jj;
        float4 bj = jb[jj];
        float aj = (bj.z - bj.x) * (bj.w - bj.y);
        float ltx = fmaxf(bi.x, bj.x), lty = fmaxf(bi.y, bj.y);
        float rbx = fminf(bi.z, bj.z), rby = fminf(bi.w, bj.w);
        float ww = fmaxf(rbx - ltx, 0.f), hh2 = fmaxf(rby - lty, 0.f);
        float inter = ww * hh2;
        float iou = inter / (ai + aj - inter);  // 0/0 -> NaN -> compare false (matches jnp)
        if ((j > i) && (j < 2000) && (iou > 0.7f)) bits |= (1ull << jj);
    }
    mask[((size_t)b * 2000 + i) * 32 + jt] = bits;
}

// ---------------------------------------------------------------------------
// K8: sequential NMS scan (1 wave per batch) + final top-300 output.
// remv word w lives in lane w; chunked (64 rows) LDS double-buffer for mask.
// ---------------------------------------------------------------------------
__global__ __launch_bounds__(64) void k_nms_scan(const float4* __restrict__ tb_boxes,
                                                 const float* __restrict__ tb_scores,
                                                 const U64* __restrict__ mask,
                                                 float* __restrict__ out) {
    int b = blockIdx.x;
    int lane = threadIdx.x;
    __shared__ U64 mbuf[2][2048];
    __shared__ unsigned short keeplist[2000];
    __shared__ unsigned char keepflag[2000];
    __shared__ unsigned short fillq[304];

    U64 remv = 0;
    if (lane < 32) {
        for (int jj = 0; jj < 64; ++jj) {
            int j = (lane << 6) | jj;
            if (j < 2000 && tb_scores[b * 2000 + j] == -INFINITY) remv |= (1ull << jj);
        }
    }
    const U64* mb = mask + (size_t)b * 2000 * 32;
#pragma unroll
    for (int q = 0; q < 32; ++q) {  // chunk 0 (rows 0..63, all valid)
        int e = q * 64 + lane;
        mbuf[0][e] = mb[(e >> 5) * 32 + (e & 31)];
    }
    __syncthreads();

    int nkeep = 0;
    for (int ch = 0; ch < 32; ++ch) {
        int cur = ch & 1;
        U64 v[32];
        if (ch < 31) {
#pragma unroll
            for (int q = 0; q < 32; ++q) {
                int e = q * 64 + lane;
                int row = (ch + 1) * 64 + (e >> 5), wd = e & 31;
                v[q] = (row < 2000) ? mb[(size_t)row * 32 + wd] : 0ull;
            }
        }
        int iend = min(64, 2000 - ch * 64);
        U64 w_all = __shfl(remv, ch);  // current suppression word (uniform)
        for (int ii = 0; ii < iend; ++ii) {
            bool sup = (w_all >> ii) & 1ull;
            int i = ch * 64 + ii;
            if (!sup) {
                if (lane == 0) keeplist[nkeep] = (unsigned short)i;
                U64 mrow = mbuf[cur][(ii << 5) | (lane & 31)];
                if (lane < 32) remv |= mrow;
                w_all |= mbuf[cur][(ii << 5) | ch];  // uniform read: same-word updates
                nkeep++;
            }
            if (lane == 0) keepflag[i] = sup ? (unsigned char)0 : (unsigned char)1;
        }
        if (ch < 31) {
#pragma unroll
            for (int q = 0; q < 32; ++q) mbuf[cur ^ 1][q * 64 + lane] = v[q];
        }
        __syncthreads();
    }

    if (lane == 0) {
        int need = 300 - nkeep, c = 0;
        for (int i = 0; i < 2000 && c < need; ++i)
            if (!keepflag[i]) fillq[c++] = (unsigned short)i;
    }
    __syncthreads();
    for (int r = lane; r < 300; r += 64) {
        int src; float sc;
        if (r < nkeep) { src = keeplist[r]; sc = tb_scores[b * 2000 + src]; }
        else           { src = fillq[r - nkeep]; sc = -INFINITY; }
        float4 bx = tb_boxes[b * 2000 + src];
        int ob = (b * 300 + r) * 4;
        out[ob + 0] = bx.x; out[ob + 1] = bx.y; out[ob + 2] = bx.z; out[ob + 3] = bx.w;
        out[4800 + b * 300 + r] = sc;
    }
}

// ---------------------------------------------------------------------------
extern "C" void kernel_launch(void* const* d_in, const int* in_sizes, int n_in,
                              void* d_out, int out_size, void* d_ws, size_t ws_size,
                              hipStream_t stream) {
    (void)in_sizes; (void)n_in; (void)out_size; (void)ws_size;
    const float* feature_map = (const float*)d_in[1];
    const float* w_conv = (const float*)d_in[2];
    const float* b_conv = (const float*)d_in[3];
    const float* w_cls  = (const float*)d_in[4];
    const float* b_cls  = (const float*)d_in[5];
    const float* w_box  = (const float*)d_in[6];
    const float* b_box  = (const float*)d_in[7];
    float* out = (float*)d_out;

    char* ws = (char*)d_ws;
    size_t off = 0;
    auto alloc = [&](size_t bytes) {
        void* p = ws + off;
        off = (off + bytes + 255) & ~(size_t)255;
        return p;
    };
    float*  wmat      = (float*) alloc(4608ull * 512 * 4);     // 9.4 MB
    float*  feat      = (float*) alloc(16384ull * 512 * 4);    // 33.6 MB
    float*  scores    = (float*) alloc(4ull * 36864 * 4);      // 0.6 MB
    float*  deltas    = (float*) alloc(4ull * 36864 * 4 * 4);  // 2.4 MB
    float4* proposals = (float4*)alloc(4ull * 36864 * 16);     // 2.4 MB
    U64*    keys      = (U64*)   alloc(4ull * 65536 * 8);      // 2.1 MB
    float4* tb_boxes  = (float4*)alloc(8000ull * 16);
    float*  tb_scores = (float*) alloc(8000ull * 4);
    U64*    nmsmask   = (U64*)   alloc(8000ull * 32 * 8);      // 2.0 MB

    k_transpose_w<<<dim3(144, 16), 256, 0, stream>>>(w_conv, wmat);
    k_conv3<<<dim3(128, 4), 256, 0, stream>>>(feature_map, wmat, b_conv, feat);
    k_heads<<<64, 256, 0, stream>>>(feat, w_cls, b_cls, w_box, b_box, scores, deltas);
    k_decode_keys<<<1024, 256, 0, stream>>>(scores, deltas, keys, proposals);

    k_sort_local<<<128, 256, 0, stream>>>(keys, 0);  // k = 2..2048
    for (int k = 4096; k <= 65536; k <<= 1) {
        for (int j = k >> 1; j >= 2048; j >>= 1)
            k_sort_global<<<512, 256, 0, stream>>>(keys, k, j);
        k_sort_local<<<128, 256, 0, stream>>>(keys, k);  // j = 1024..1
    }

    k_topk_gather<<<32, 256, 0, stream>>>(keys, proposals, tb_boxes, tb_scores);
    k_nms_mask<<<dim3(32, 32, 4), 64, 0, stream>>>(tb_boxes, nmsmask);
    k_nms_scan<<<4, 64, 0, stream>>>(tb_boxes, tb_scores, nmsmask, out);
}

// Round 3
// 823.699 us; speedup vs baseline: 2.4298x; 2.4298x over previous
//
#include <hip/hip_runtime.h>
#include <math.h>

typedef unsigned long long U64;
typedef _Float16 half8 __attribute__((ext_vector_type(8)));
typedef float f32x16 __attribute__((ext_vector_type(16)));

__device__ const float g_bw[9] = {91.f, 181.f, 362.f, 64.f, 128.f, 256.f, 45.f, 91.f, 181.f};
__device__ const float g_bh[9] = {45.f, 91.f, 181.f, 64.f, 128.f, 256.f, 91.f, 181.f, 362.f};

__device__ inline f32x16 zero16() {
    f32x16 z;
#pragma unroll
    for (int i = 0; i < 16; ++i) z[i] = 0.f;
    return z;
}

// ---------------------------------------------------------------------------
// K_prep_fm: fm NCHW f32 -> padded NHWC f16 hi/lo planes [4][66][66][512].
// Halo pre-zeroed by hipMemsetAsync. grid (8 cgroups, 64 h, 4 b), 256 thr.
// ---------------------------------------------------------------------------
__global__ __launch_bounds__(256) void k_prep_fm(const float* __restrict__ fm,
                                                 _Float16* __restrict__ fph,
                                                 _Float16* __restrict__ fpl) {
    __shared__ float tile[64][65];
    int cg = blockIdx.x, h = blockIdx.y, b = blockIdx.z;
    int t = threadIdx.x;
    int cl = t >> 2, w0 = (t & 3) * 16;
    const float* src = fm + (((size_t)(b * 512 + cg * 64 + cl) * 64 + h) * 64 + w0);
#pragma unroll
    for (int l = 0; l < 4; ++l) {
        float4 v = *(const float4*)(src + l * 4);
        tile[cl][w0 + l * 4 + 0] = v.x; tile[cl][w0 + l * 4 + 1] = v.y;
        tile[cl][w0 + l * 4 + 2] = v.z; tile[cl][w0 + l * 4 + 3] = v.w;
    }
    __syncthreads();
    int wI = t >> 2, c0l = (t & 3) * 16;
    size_t dst = ((size_t)(b * 66 + h + 1) * 66 + (wI + 1)) * 512 + cg * 64 + c0l;
#pragma unroll
    for (int pair = 0; pair < 2; ++pair) {
        half8 hv, lv;
#pragma unroll
        for (int i = 0; i < 8; ++i) {
            float x = tile[c0l + pair * 8 + i][wI];
            _Float16 hi = (_Float16)x;
            hv[i] = hi;
            lv[i] = (_Float16)((x - (float)hi) * 2048.0f);
        }
        *(half8*)(fph + dst + pair * 8) = hv;
        *(half8*)(fpl + dst + pair * 8) = lv;
    }
}

// ---------------------------------------------------------------------------
// K_prep_w: w_conv [512 o][512 c][9 r] f32 -> wk[o][k=r*512+c] f16 hi/lo.
// ---------------------------------------------------------------------------
__global__ __launch_bounds__(256) void k_prep_w(const float* __restrict__ w_conv,
                                                _Float16* __restrict__ wkh,
                                                _Float16* __restrict__ wkl) {
    __shared__ float wb[4608];
    int o = blockIdx.x, t = threadIdx.x;
    for (int e = t; e < 4608; e += 256) wb[e] = w_conv[(size_t)o * 4608 + e];
    __syncthreads();
    for (int e = t; e < 4608; e += 256) {
        int c = e & 511, r = e >> 9;
        float x = wb[c * 9 + r];
        _Float16 hi = (_Float16)x;
        wkh[(size_t)o * 4608 + e] = hi;
        wkl[(size_t)o * 4608 + e] = (_Float16)((x - (float)hi) * 2048.0f);
    }
}

// ---------------------------------------------------------------------------
// K_conv_mfma: implicit-GEMM 3x3 conv via mfma_f32_32x32x16_f16, hi/lo split.
// M=16384 px, N=512, K=4608 (k = r*512+c). Block 128x128, 4 waves, 64x64/wave.
// LDS row = [hi k0..31 | lo k0..31] f16 = 128 B, XOR swizzle byte^=(row&7)<<4.
// ---------------------------------------------------------------------------
__global__ __launch_bounds__(256, 2) void k_conv_mfma(
    const _Float16* __restrict__ fph, const _Float16* __restrict__ fpl,
    const _Float16* __restrict__ wkh, const _Float16* __restrict__ wkl,
    const float* __restrict__ bconv, float* __restrict__ feat) {
    __shared__ _Float16 As[2][128][64];
    __shared__ _Float16 Bs[2][128][64];
    const int t = threadIdx.x;
    const int lane = t & 63, wv = t >> 6;
    const int wm = wv >> 1, wn = wv & 1;
    const int p0 = blockIdx.x * 128, o0 = blockIdx.y * 128;

    // staging map: thread covers rows {srow, 64+srow}, one 16B slot per (h2,hl)
    const int srow = t >> 2;
    const int scol = (t & 3) * 8;  // f16 elems within 32-elem half
    int idxA[2], idxB[2], woff[2][2];
#pragma unroll
    for (int h2 = 0; h2 < 2; ++h2) {
        int r = h2 * 64 + srow;
        int P = p0 + r;
        int bb = P >> 12, hh = (P >> 6) & 63, ww = P & 63;
        idxA[h2] = ((bb * 66 + hh) * 66 + ww) * 512 + scol;
        idxB[h2] = (o0 + r) * 4608 + scol;
        woff[h2][0] = r * 128 + ((((t & 3) + 0) * 16) ^ ((r & 7) << 4));
        woff[h2][1] = r * 128 + ((((t & 3) + 4) * 16) ^ ((r & 7) << 4));
    }

    f32x16 acc0[2][2], acc1[2][2];
#pragma unroll
    for (int mi = 0; mi < 2; ++mi)
#pragma unroll
        for (int ni = 0; ni < 2; ++ni) { acc0[mi][ni] = zero16(); acc1[mi][ni] = zero16(); }

    half8 sa[2][2], sb[2][2];  // [h2][hl]
    auto stage = [&](int k0) {
        int rr = k0 >> 9, c0 = k0 & 511;
        int ry = (rr * 11) >> 5, rx = rr - ry * 3;
        int koffA = (ry * 66 + rx) * 512 + c0;
#pragma unroll
        for (int h2 = 0; h2 < 2; ++h2) {
            sa[h2][0] = *(const half8*)(fph + idxA[h2] + koffA);
            sa[h2][1] = *(const half8*)(fpl + idxA[h2] + koffA);
            sb[h2][0] = *(const half8*)(wkh + idxB[h2] + k0);
            sb[h2][1] = *(const half8*)(wkl + idxB[h2] + k0);
        }
    };
    auto commit = [&](int buf) {
        char* ab = (char*)As + buf * 16384;
        char* bb = (char*)Bs + buf * 16384;
#pragma unroll
        for (int h2 = 0; h2 < 2; ++h2) {
            *(half8*)(ab + woff[h2][0]) = sa[h2][0];
            *(half8*)(ab + woff[h2][1]) = sa[h2][1];
            *(half8*)(bb + woff[h2][0]) = sb[h2][0];
            *(half8*)(bb + woff[h2][1]) = sb[h2][1];
        }
    };

    stage(0);
    commit(0);
    __syncthreads();

    for (int it = 0; it < 144; ++it) {
        int cur = it & 1;
        if (it < 143) stage((it + 1) * 32);
        const char* ab = (const char*)As + cur * 16384;
        const char* bb = (const char*)Bs + cur * 16384;
        half8 af[2][2][2], bf[2][2][2];  // [idx][hl][kh]
        const int lg = (lane >> 5) * 16;
#pragma unroll
        for (int mi = 0; mi < 2; ++mi) {
            int rA = wm * 64 + mi * 32 + (lane & 31);
            int xa = (rA & 7) << 4, ba = rA * 128;
#pragma unroll
            for (int hl = 0; hl < 2; ++hl)
#pragma unroll
                for (int kh = 0; kh < 2; ++kh)
                    af[mi][hl][kh] = *(const half8*)(ab + ba + ((hl * 64 + kh * 32 + lg) ^ xa));
        }
#pragma unroll
        for (int ni = 0; ni < 2; ++ni) {
            int rB = wn * 64 + ni * 32 + (lane & 31);
            int xb = (rB & 7) << 4, bb0 = rB * 128;
#pragma unroll
            for (int hl = 0; hl < 2; ++hl)
#pragma unroll
                for (int kh = 0; kh < 2; ++kh)
                    bf[ni][hl][kh] = *(const half8*)(bb + bb0 + ((hl * 64 + kh * 32 + lg) ^ xb));
        }
#pragma unroll
        for (int mi = 0; mi < 2; ++mi)
#pragma unroll
            for (int ni = 0; ni < 2; ++ni) {
                acc0[mi][ni] = __builtin_amdgcn_mfma_f32_32x32x16_f16(af[mi][0][0], bf[ni][0][0], acc0[mi][ni], 0, 0, 0);
                acc0[mi][ni] = __builtin_amdgcn_mfma_f32_32x32x16_f16(af[mi][0][1], bf[ni][0][1], acc0[mi][ni], 0, 0, 0);
                acc1[mi][ni] = __builtin_amdgcn_mfma_f32_32x32x16_f16(af[mi][0][0], bf[ni][1][0], acc1[mi][ni], 0, 0, 0);
                acc1[mi][ni] = __builtin_amdgcn_mfma_f32_32x32x16_f16(af[mi][0][1], bf[ni][1][1], acc1[mi][ni], 0, 0, 0);
                acc1[mi][ni] = __builtin_amdgcn_mfma_f32_32x32x16_f16(af[mi][1][0], bf[ni][0][0], acc1[mi][ni], 0, 0, 0);
                acc1[mi][ni] = __builtin_amdgcn_mfma_f32_32x32x16_f16(af[mi][1][1], bf[ni][0][1], acc1[mi][ni], 0, 0, 0);
            }
        if (it < 143) commit(cur ^ 1);
        __syncthreads();
    }

    // epilogue: combine + bias + relu, C/D map col=lane&31, row=(q&3)+8*(q>>2)+4*(lane>>5)
#pragma unroll
    for (int mi = 0; mi < 2; ++mi)
#pragma unroll
        for (int ni = 0; ni < 2; ++ni) {
            int col = o0 + wn * 64 + ni * 32 + (lane & 31);
            float bv = bconv[col];
            int rbase = p0 + wm * 64 + mi * 32 + 4 * (lane >> 5);
#pragma unroll
            for (int q = 0; q < 16; ++q) {
                int row = rbase + (q & 3) + 8 * (q >> 2);
                float v = acc0[mi][ni][q] + acc1[mi][ni][q] * 4.8828125e-4f + bv;
                feat[(size_t)row * 512 + col] = fmaxf(v, 0.f);
            }
        }
}

// ---------------------------------------------------------------------------
// K_heads: 1x1 heads, 4-way channel split per pixel + LDS reduce.
// grid 256 blocks x 256 thr; block = 64 pixels x 4 c-quarters.
// ---------------------------------------------------------------------------
__global__ __launch_bounds__(256) void k_heads(const float* __restrict__ feat,
                                               const float* __restrict__ w_cls,
                                               const float* __restrict__ b_cls,
                                               const float* __restrict__ w_box,
                                               const float* __restrict__ b_box,
                                               float* __restrict__ scores,
                                               float* __restrict__ deltas) {
    __shared__ float red[3][64][45];
    int t = threadIdx.x;
    int px = t & 63, cq = t >> 6;
    int p = blockIdx.x * 64 + px;
    const float* fr = feat + (size_t)p * 512 + cq * 128;
    float acc[45];
#pragma unroll
    for (int o = 0; o < 45; ++o) acc[o] = 0.f;
    for (int c = 0; c < 128; c += 4) {
        float4 f = *(const float4*)(fr + c);
#pragma unroll
        for (int o = 0; o < 45; ++o) {
            const float* wr = ((o < 9) ? (w_cls + o * 512) : (w_box + (o - 9) * 512)) + cq * 128 + c;
            acc[o] += f.x * wr[0] + f.y * wr[1] + f.z * wr[2] + f.w * wr[3];
        }
    }
    if (cq > 0) {
#pragma unroll
        for (int o = 0; o < 45; ++o) red[cq - 1][px][o] = acc[o];
    }
    __syncthreads();
    if (cq == 0) {
#pragma unroll
        for (int o = 0; o < 45; ++o) acc[o] += red[0][px][o] + red[1][px][o] + red[2][px][o];
        int b = p >> 12, pixloc = p & 4095;
        int sbase = b * 36864 + pixloc * 9;
#pragma unroll
        for (int o = 0; o < 9; ++o) {
            float x = acc[o] + b_cls[o];
            scores[sbase + o] = 1.f / (1.f + expf(-x));
        }
#pragma unroll
        for (int c36 = 0; c36 < 36; ++c36) {
            float x = acc[9 + c36] + b_box[c36];
            int a = c36 >> 2, comp = c36 & 3;
            deltas[(size_t)(sbase + a) * 4 + comp] = x;
        }
    }
}

// ---------------------------------------------------------------------------
// K_decode_keys: decode proposals + build sort keys (no padding; N=36864).
// key = (score_bits ^ 0x80000000)<<32 | ~index -> desc sort == stable top_k.
// ---------------------------------------------------------------------------
__global__ __launch_bounds__(256) void k_decode_keys(const float* __restrict__ scores,
                                                     const float* __restrict__ deltas,
                                                     U64* __restrict__ keys,
                                                     float4* __restrict__ proposals) {
    int i = blockIdx.x * 256 + threadIdx.x;  // 0..36863
    int b = blockIdx.y;
    float s = scores[b * 36864 + i];
    keys[b * 36864 + i] =
        (((U64)(__float_as_uint(s) ^ 0x80000000u)) << 32) | (unsigned)(~(unsigned)i);
    int pix = i / 9;
    int a = i - pix * 9;
    int h = pix >> 6, w = pix & 63;
    float bw = g_bw[a], bh = g_bh[a];
    float cxa = (float)(w * 16), cya = (float)(h * 16);
    float wa = 2.f * bw, ha = 2.f * bh;
    const float4 d = *(const float4*)(deltas + (size_t)(b * 36864 + i) * 4);
    float dw = fminf(d.z, 4.135166556742356f);
    float dh = fminf(d.w, 4.135166556742356f);
    float cx = d.x * wa + cxa;
    float cy = d.y * ha + cya;
    float pw = expf(dw) * wa;
    float ph = expf(dh) * ha;
    proposals[b * 36864 + i] =
        make_float4(cx - 0.5f * pw, cy - 0.5f * ph, cx + 0.5f * pw, cy + 0.5f * ph);
}

// ---------------------------------------------------------------------------
// Sort: 18 chunk-sorts of 2048 (36864 = 18*2048) + 5 merge-truncate rounds.
// ---------------------------------------------------------------------------
__device__ inline void cmp_stage(U64* s, int j, int k, int tid) {
    for (int p = tid; p < 1024; p += 256) {
        int il = ((p & ~(j - 1)) << 1) | (p & (j - 1));
        int ip = il | j;
        U64 a = s[il], c = s[ip];
        bool desc = ((il & k) == 0);
        bool sw = desc ? (a < c) : (a > c);
        if (sw) { s[il] = c; s[ip] = a; }
    }
}

__global__ __launch_bounds__(256) void k_sort_chunk(const U64* __restrict__ keys,
                                                    U64* __restrict__ run) {
    __shared__ U64 s[2048];
    int b = blockIdx.x / 18, ch = blockIdx.x % 18;
    int tid = threadIdx.x;
    const U64* src = keys + (size_t)b * 36864 + ch * 2048;
    for (int e = tid; e < 2048; e += 256) s[e] = src[e];
    __syncthreads();
    for (int k = 2; k <= 2048; k <<= 1)
        for (int j = k >> 1; j >= 1; j >>= 1) {
            cmp_stage(s, j, k, tid);
            __syncthreads();
        }
    U64* dst = run + ((size_t)b * 18 + ch) * 2048;
    for (int e = tid; e < 2048; e += 256) dst[e] = s[e];
}

// merge two sorted-desc 2048 runs -> top-2048 desc (bitonic merge of 4096)
__global__ __launch_bounds__(256) void k_merge(const U64* __restrict__ in,
                                               U64* __restrict__ out, int nc) {
    __shared__ U64 s[4096];
    int j = blockIdx.x, b = blockIdx.y;
    int tid = threadIdx.x;
    const U64* A = in + ((size_t)b * 18 + 2 * j) * 2048;
    U64* O = out + ((size_t)b * 18 + j) * 2048;
    if (2 * j + 1 < nc) {
        const U64* Bp = in + ((size_t)b * 18 + 2 * j + 1) * 2048;
        for (int e = tid; e < 2048; e += 256) { s[e] = A[e]; s[4095 - e] = Bp[e]; }
        __syncthreads();
        for (int jj = 2048; jj >= 1; jj >>= 1) {
            for (int p = tid; p < 2048; p += 256) {
                int il = ((p & ~(jj - 1)) << 1) | (p & (jj - 1));
                int ip = il | jj;
                U64 a = s[il], c = s[ip];
                if (a < c) { s[il] = c; s[ip] = a; }
            }
            __syncthreads();
        }
        for (int e = tid; e < 2048; e += 256) O[e] = s[e];
    } else {
        for (int e = tid; e < 2048; e += 256) O[e] = A[e];
    }
}

// ---------------------------------------------------------------------------
// K_topk_gather: top-2000/batch from final run, clip, min-size filter.
// ---------------------------------------------------------------------------
__global__ __launch_bounds__(256) void k_topk_gather(const U64* __restrict__ runf,
                                                     const float4* __restrict__ proposals,
                                                     float4* __restrict__ tb_boxes,
                                                     float* __restrict__ tb_scores) {
    int g = blockIdx.x * 256 + threadIdx.x;
    if (g >= 8000) return;
    int b = g / 2000, r = g - b * 2000;
    U64 key = runf[(size_t)b * 18 * 2048 + r];
    unsigned n = ~((unsigned)key);
    float s = __uint_as_float(((unsigned)(key >> 32)) ^ 0x80000000u);
    float4 p = proposals[b * 36864 + (int)n];
    float x1 = fminf(fmaxf(p.x, 0.f), 1024.f);
    float y1 = fminf(fmaxf(p.y, 0.f), 1024.f);
    float x2 = fminf(fmaxf(p.z, 0.f), 1024.f);
    float y2 = fminf(fmaxf(p.w, 0.f), 1024.f);
    bool small_ = ((x2 - x1) < 16.f) || ((y2 - y1) < 16.f);
    tb_boxes[g] = make_float4(x1, y1, x2, y2);
    tb_scores[g] = small_ ? -INFINITY : s;
}

// ---------------------------------------------------------------------------
// K_nms_mask: suppression bitmask. mask[b][i][jt] bit jj = (j>i && iou>0.7).
// ---------------------------------------------------------------------------
__global__ __launch_bounds__(64) void k_nms_mask(const float4* __restrict__ tb_boxes,
                                                 U64* __restrict__ mask) {
    int jt = blockIdx.x, it = blockIdx.y, b = blockIdx.z;
    int tid = threadIdx.x;
    __shared__ float4 jb[64];
    int j0 = jt * 64;
    {
        int j = j0 + tid;
        jb[tid] = (j < 2000) ? tb_boxes[b * 2000 + j] : make_float4(0.f, 0.f, 0.f, 0.f);
    }
    __syncthreads();
    int i = it * 64 + tid;
    if (i >= 2000) return;
    float4 bi = tb_boxes[b * 2000 + i];
    float ai = (bi.z - bi.x) * (bi.w - bi.y);
    U64 bits = 0;
#pragma unroll 4
    for (int jj = 0; jj < 64; ++jj) {
        int j = j0 + jj;
        float4 bj = jb[jj];
        float aj = (bj.z - bj.x) * (bj.w - bj.y);
        float ltx = fmaxf(bi.x, bj.x), lty = fmaxf(bi.y, bj.y);
        float rbx = fminf(bi.z, bj.z), rby = fminf(bi.w, bj.w);
        float ww = fmaxf(rbx - ltx, 0.f), hh2 = fmaxf(rby - lty, 0.f);
        float inter = ww * hh2;
        float iou = inter / (ai + aj - inter);
        if ((j > i) && (j < 2000) && (iou > 0.7f)) bits |= (1ull << jj);
    }
    mask[((size_t)b * 2000 + i) * 32 + jt] = bits;
}

// ---------------------------------------------------------------------------
// K_nms_scan: sequential NMS scan (1 wave/batch) + final top-300 output.
// ---------------------------------------------------------------------------
__global__ __launch_bounds__(64) void k_nms_scan(const float4* __restrict__ tb_boxes,
                                                 const float* __restrict__ tb_scores,
                                                 const U64* __restrict__ mask,
                                                 float* __restrict__ out) {
    int b = blockIdx.x;
    int lane = threadIdx.x;
    __shared__ U64 mbuf[2][2048];
    __shared__ unsigned short keeplist[2000];
    __shared__ unsigned char keepflag[2000];
    __shared__ unsigned short fillq[304];

    U64 remv = 0;
    if (lane < 32) {
        for (int jj = 0; jj < 64; ++jj) {
            int j = (lane << 6) | jj;
            if (j < 2000 && tb_scores[b * 2000 + j] == -INFINITY) remv |= (1ull << jj);
        }
    }
    const U64* mb = mask + (size_t)b * 2000 * 32;
#pragma unroll
    for (int q = 0; q < 32; ++q) {
        int e = q * 64 + lane;
        mbuf[0][e] = mb[(e >> 5) * 32 + (e & 31)];
    }
    __syncthreads();

    int nkeep = 0;
    for (int ch = 0; ch < 32; ++ch) {
        int cur = ch & 1;
        U64 v[32];
        if (ch < 31) {
#pragma unroll
            for (int q = 0; q < 32; ++q) {
                int e = q * 64 + lane;
                int row = (ch + 1) * 64 + (e >> 5), wd = e & 31;
                v[q] = (row < 2000) ? mb[(size_t)row * 32 + wd] : 0ull;
            }
        }
        int iend = min(64, 2000 - ch * 64);
        U64 w_all = __shfl(remv, ch);
        for (int ii = 0; ii < iend; ++ii) {
            bool sup = (w_all >> ii) & 1ull;
            int i = ch * 64 + ii;
            if (!sup) {
                if (lane == 0) keeplist[nkeep] = (unsigned short)i;
                U64 mrow = mbuf[cur][(ii << 5) | (lane & 31)];
                if (lane < 32) remv |= mrow;
                w_all |= mbuf[cur][(ii << 5) | ch];
                nkeep++;
            }
            if (lane == 0) keepflag[i] = sup ? (unsigned char)0 : (unsigned char)1;
        }
        if (ch < 31) {
#pragma unroll
            for (int q = 0; q < 32; ++q) mbuf[cur ^ 1][q * 64 + lane] = v[q];
        }
        __syncthreads();
    }

    if (lane == 0) {
        int need = 300 - nkeep, c = 0;
        for (int i = 0; i < 2000 && c < need; ++i)
            if (!keepflag[i]) fillq[c++] = (unsigned short)i;
    }
    __syncthreads();
    for (int r = lane; r < 300; r += 64) {
        int src; float sc;
        if (r < nkeep) { src = keeplist[r]; sc = tb_scores[b * 2000 + src]; }
        else           { src = fillq[r - nkeep]; sc = -INFINITY; }
        float4 bx = tb_boxes[b * 2000 + src];
        int ob = (b * 300 + r) * 4;
        out[ob + 0] = bx.x; out[ob + 1] = bx.y; out[ob + 2] = bx.z; out[ob + 3] = bx.w;
        out[4800 + b * 300 + r] = sc;
    }
}

// ---------------------------------------------------------------------------
extern "C" void kernel_launch(void* const* d_in, const int* in_sizes, int n_in,
                              void* d_out, int out_size, void* d_ws, size_t ws_size,
                              hipStream_t stream) {
    (void)in_sizes; (void)n_in; (void)out_size; (void)ws_size;
    const float* feature_map = (const float*)d_in[1];
    const float* w_conv = (const float*)d_in[2];
    const float* b_conv = (const float*)d_in[3];
    const float* w_cls  = (const float*)d_in[4];
    const float* b_cls  = (const float*)d_in[5];
    const float* w_box  = (const float*)d_in[6];
    const float* b_box  = (const float*)d_in[7];
    float* out = (float*)d_out;

    char* ws = (char*)d_ws;
    size_t off = 0;
    auto alloc = [&](size_t bytes) {
        void* p = ws + off;
        off = (off + bytes + 255) & ~(size_t)255;
        return p;
    };
    const size_t fp_elems = 4ull * 66 * 66 * 512;
    _Float16* fph = (_Float16*)alloc(fp_elems * 2);            // 17.8 MB
    _Float16* fpl = (_Float16*)alloc(fp_elems * 2);            // 17.8 MB
    _Float16* wkh = (_Float16*)alloc(512ull * 4608 * 2);       // 4.7 MB
    _Float16* wkl = (_Float16*)alloc(512ull * 4608 * 2);       // 4.7 MB
    float*  feat      = (float*) alloc(16384ull * 512 * 4);    // 33.6 MB
    float*  scores    = (float*) alloc(4ull * 36864 * 4);
    float*  deltas    = (float*) alloc(4ull * 36864 * 4 * 4);
    float4* proposals = (float4*)alloc(4ull * 36864 * 16);
    U64*    keys      = (U64*)   alloc(4ull * 36864 * 8);
    U64*    run0      = (U64*)   alloc(4ull * 18 * 2048 * 8);
    U64*    run1      = (U64*)   alloc(4ull * 18 * 2048 * 8);
    float4* tb_boxes  = (float4*)alloc(8000ull * 16);
    float*  tb_scores = (float*) alloc(8000ull * 4);
    U64*    nmsmask   = (U64*)   alloc(8000ull * 32 * 8);

    hipMemsetAsync(fph, 0, fp_elems * 2, stream);
    hipMemsetAsync(fpl, 0, fp_elems * 2, stream);
    k_prep_fm<<<dim3(8, 64, 4), 256, 0, stream>>>(feature_map, fph, fpl);
    k_prep_w<<<512, 256, 0, stream>>>(w_conv, wkh, wkl);
    k_conv_mfma<<<dim3(128, 4), 256, 0, stream>>>(fph, fpl, wkh, wkl, b_conv, feat);
    k_heads<<<256, 256, 0, stream>>>(feat, w_cls, b_cls, w_box, b_box, scores, deltas);
    k_decode_keys<<<dim3(144, 4), 256, 0, stream>>>(scores, deltas, keys, proposals);

    k_sort_chunk<<<72, 256, 0, stream>>>(keys, run0);
    U64* bufs[2] = {run0, run1};
    int nc = 18, src = 0;
    while (nc > 1) {
        int nm = (nc + 1) / 2;
        k_merge<<<dim3(nm, 4), 256, 0, stream>>>(bufs[src], bufs[src ^ 1], nc);
        src ^= 1;
        nc = nm;
    }
    k_topk_gather<<<32, 256, 0, stream>>>(bufs[src], proposals, tb_boxes, tb_scores);
    k_nms_mask<<<dim3(32, 32, 4), 64, 0, stream>>>(tb_boxes, nmsmask);
    k_nms_scan<<<4, 64, 0, stream>>>(tb_boxes, tb_scores, nmsmask, out);
}

// Round 5
// 786.838 us; speedup vs baseline: 2.5436x; 1.0468x over previous
//
#include <hip/hip_runtime.h>
#include <math.h>

typedef unsigned long long U64;
typedef _Float16 half8 __attribute__((ext_vector_type(8)));
typedef float f32x16 __attribute__((ext_vector_type(16)));

__device__ const float g_bw[9] = {91.f, 181.f, 362.f, 64.f, 128.f, 256.f, 45.f, 91.f, 181.f};
__device__ const float g_bh[9] = {45.f, 91.f, 181.f, 64.f, 128.f, 256.f, 91.f, 181.f, 362.f};

__device__ inline f32x16 zero16() {
    f32x16 z;
#pragma unroll
    for (int i = 0; i < 16; ++i) z[i] = 0.f;
    return z;
}

#define GLOAD16(G, L)                                                  \
    __builtin_amdgcn_global_load_lds(                                  \
        (const __attribute__((address_space(1))) void*)(G),            \
        (__attribute__((address_space(3))) void*)(L), 16, 0, 0)

// ---------------------------------------------------------------------------
// K_prep_fm: fm NCHW f32 -> padded interleaved f16 planes
// fpi[b][hp 0..65][wp 0..65][chunk 0..15][64] ; chunk inner = [hi x32 | lo x32]
// Halo pre-zeroed by one hipMemsetAsync. grid (8 cg64, 64 h, 4 b), 256 thr.
// ---------------------------------------------------------------------------
__global__ __launch_bounds__(256) void k_prep_fm(const float* __restrict__ fm,
                                                 _Float16* __restrict__ fpi) {
    __shared__ float tile[64][65];
    int cg = blockIdx.x, h = blockIdx.y, b = blockIdx.z;
    int t = threadIdx.x;
    int cl = t >> 2, w0 = (t & 3) * 16;
    const float* src = fm + (((size_t)(b * 512 + cg * 64 + cl) * 64 + h) * 64 + w0);
#pragma unroll
    for (int l = 0; l < 4; ++l) {
        float4 v = *(const float4*)(src + l * 4);
        tile[cl][w0 + l * 4 + 0] = v.x; tile[cl][w0 + l * 4 + 1] = v.y;
        tile[cl][w0 + l * 4 + 2] = v.z; tile[cl][w0 + l * 4 + 3] = v.w;
    }
    __syncthreads();
    int w = t & 63, pth = t >> 6;
    int chunkrel = pth >> 1, half = pth & 1;
    _Float16* dst = fpi + ((size_t)((b * 66 + h + 1) * 66) + (w + 1)) * 1024 +
                    (cg * 2 + chunkrel) * 64 + half * 32;
#pragma unroll
    for (int g8 = 0; g8 < 4; ++g8) {
        half8 v;
#pragma unroll
        for (int i = 0; i < 8; ++i) {
            float x = tile[chunkrel * 32 + g8 * 8 + i][w];
            _Float16 hi = (_Float16)x;
            v[i] = half ? (_Float16)((x - (float)hi) * 2048.0f) : hi;
        }
        *(half8*)(dst + g8 * 8) = v;
    }
}

// ---------------------------------------------------------------------------
// K_prep_w: w_conv [512 o][512 c][9 tap] f32 -> wki[o][chunk=tap*16+cg][64]
// chunk inner = [hi x32 | lo x32] f16. One block per o.
// ---------------------------------------------------------------------------
__global__ __launch_bounds__(256) void k_prep_w(const float* __restrict__ w_conv,
                                                _Float16* __restrict__ wki) {
    __shared__ float wb[4608];
    int o = blockIdx.x, t = threadIdx.x;
    for (int e = t; e < 4608; e += 256) wb[e] = w_conv[(size_t)o * 4608 + e];
    __syncthreads();
    for (int e = t; e < 9216; e += 256) {
        int s = e & 63, chunk = e >> 6;
        int tap = chunk >> 4, cgi = chunk & 15;
        int c = cgi * 32 + (s & 31);
        float x = wb[c * 9 + tap];
        _Float16 hi = (_Float16)x;
        wki[(size_t)o * 9216 + e] = (s < 32) ? hi : (_Float16)((x - (float)hi) * 2048.0f);
    }
}

// ---------------------------------------------------------------------------
// K_conv_mfma: implicit-GEMM 3x3 conv via mfma_f32_32x32x16_f16, hi/lo split.
// M=16384 px, N=512, K=4608. Block 128x128, 4 waves, 64x64/wave, BK=32(x hi/lo).
// Staging via global_load_lds (linear LDS dest, inverse-swizzled global src,
// swizzled read: physical slot p of row r holds logical slot p^(r&7)).
// Double-buffered with counted s_waitcnt vmcnt(8) (T4): next-buf DMA stays
// in flight across barriers.
// ---------------------------------------------------------------------------
__global__ __launch_bounds__(256, 2) void k_conv_mfma(
    const _Float16* __restrict__ fpi, const _Float16* __restrict__ wki,
    const float* __restrict__ bconv, float* __restrict__ feat) {
    __shared__ _Float16 As[2][128][64];
    __shared__ _Float16 Bs[2][128][64];
    const int t = threadIdx.x;
    const int lane = t & 63, wv = t >> 6;
    const int wm = wv >> 1, wn = wv & 1;
    // XCD-aware swizzle (512 blocks, 8 XCDs, pixel-major within XCD chunk)
    int flat = (int)blockIdx.x + 128 * (int)blockIdx.y;
    int fid = (flat & 7) * 64 + (flat >> 3);
    const int p0 = (fid >> 2) * 128, o0 = (fid & 3) * 128;

    // staging bases: wave wv instr q covers rows wv*32+q*8 .. +7
    // lane covers row = +(lane>>3), physical slot p = lane&7, logical qs = p^(row&7)
    const char* baseA[4];
    const char* baseB[4];
#pragma unroll
    for (int q = 0; q < 4; ++q) {
        int row = wv * 32 + q * 8 + (lane >> 3);
        int qs = (lane & 7) ^ (row & 7);
        int P = p0 + row;
        int bb = P >> 12, hh = (P >> 6) & 63, ww = P & 63;
        baseA[q] = (const char*)fpi + ((size_t)((bb * 66 + hh) * 66 + ww)) * 2048 + qs * 16;
        baseB[q] = (const char*)wki + (size_t)(o0 + row) * 18432 + qs * 16;
    }

    f32x16 acc0[2][2], acc1[2][2];
#pragma unroll
    for (int mi = 0; mi < 2; ++mi)
#pragma unroll
        for (int ni = 0; ni < 2; ++ni) { acc0[mi][ni] = zero16(); acc1[mi][ni] = zero16(); }

    auto issue = [&](int it2, int buf) {
        int tap = it2 >> 4;
        int ry = (tap * 11) >> 5, rx = tap - ry * 3;
        int ka = (ry * 66 + rx) * 2048 + (it2 & 15) * 128;
        int kb = it2 * 128;
#pragma unroll
        for (int q = 0; q < 4; ++q) {
            GLOAD16(baseA[q] + ka, &As[buf][wv * 32 + q * 8][0]);
            GLOAD16(baseB[q] + kb, &Bs[buf][wv * 32 + q * 8][0]);
        }
    };

    issue(0, 0);
    issue(1, 1);

    for (int it = 0; it < 144; ++it) {
        int cur = it & 1;
        if (it < 143) { asm volatile("s_waitcnt vmcnt(8)" ::: "memory"); }
        else          { asm volatile("s_waitcnt vmcnt(0)" ::: "memory"); }
        __builtin_amdgcn_s_barrier();
        __builtin_amdgcn_sched_barrier(0);

        const char* ab = (const char*)As + cur * 16384;
        const char* bb2 = (const char*)Bs + cur * 16384;
        half8 af[2][2][2], bf[2][2][2];  // [idx][hl][kh]
        const int lg = (lane >> 5) * 16;
#pragma unroll
        for (int mi = 0; mi < 2; ++mi) {
            int rA = wm * 64 + mi * 32 + (lane & 31);
            int xa = (rA & 7) << 4, ba = rA * 128;
#pragma unroll
            for (int hl = 0; hl < 2; ++hl)
#pragma unroll
                for (int kh = 0; kh < 2; ++kh)
                    af[mi][hl][kh] = *(const half8*)(ab + ba + ((hl * 64 + kh * 32 + lg) ^ xa));
        }
#pragma unroll
        for (int ni = 0; ni < 2; ++ni) {
            int rB = wn * 64 + ni * 32 + (lane & 31);
            int xb = (rB & 7) << 4, bb0 = rB * 128;
#pragma unroll
            for (int hl = 0; hl < 2; ++hl)
#pragma unroll
                for (int kh = 0; kh < 2; ++kh)
                    bf[ni][hl][kh] = *(const half8*)(bb2 + bb0 + ((hl * 64 + kh * 32 + lg) ^ xb));
        }
#pragma unroll
        for (int mi = 0; mi < 2; ++mi)
#pragma unroll
            for (int ni = 0; ni < 2; ++ni) {
                acc0[mi][ni] = __builtin_amdgcn_mfma_f32_32x32x16_f16(af[mi][0][0], bf[ni][0][0], acc0[mi][ni], 0, 0, 0);
                acc0[mi][ni] = __builtin_amdgcn_mfma_f32_32x32x16_f16(af[mi][0][1], bf[ni][0][1], acc0[mi][ni], 0, 0, 0);
                acc1[mi][ni] = __builtin_amdgcn_mfma_f32_32x32x16_f16(af[mi][0][0], bf[ni][1][0], acc1[mi][ni], 0, 0, 0);
                acc1[mi][ni] = __builtin_amdgcn_mfma_f32_32x32x16_f16(af[mi][0][1], bf[ni][1][1], acc1[mi][ni], 0, 0, 0);
                acc1[mi][ni] = __builtin_amdgcn_mfma_f32_32x32x16_f16(af[mi][1][0], bf[ni][0][0], acc1[mi][ni], 0, 0, 0);
                acc1[mi][ni] = __builtin_amdgcn_mfma_f32_32x32x16_f16(af[mi][1][1], bf[ni][0][1], acc1[mi][ni], 0, 0, 0);
            }

        __builtin_amdgcn_sched_barrier(0);
        __builtin_amdgcn_s_barrier();
        __builtin_amdgcn_sched_barrier(0);
        if (it < 142) issue(it + 2, cur);
    }

    // epilogue: combine + bias + relu; C/D map col=lane&31, row=(q&3)+8*(q>>2)+4*(lane>>5)
#pragma unroll
    for (int mi = 0; mi < 2; ++mi)
#pragma unroll
        for (int ni = 0; ni < 2; ++ni) {
            int col = o0 + wn * 64 + ni * 32 + (lane & 31);
            float bv = bconv[col];
            int rbase = p0 + wm * 64 + mi * 32 + 4 * (lane >> 5);
#pragma unroll
            for (int q = 0; q < 16; ++q) {
                int row = rbase + (q & 3) + 8 * (q >> 2);
                float v = acc0[mi][ni][q] + acc1[mi][ni][q] * 4.8828125e-4f + bv;
                feat[(size_t)row * 512 + col] = fmaxf(v, 0.f);
            }
        }
}

// ---------------------------------------------------------------------------
// K_heads: 1x1 heads (4-way channel split + LDS reduce) FUSED with sigmoid,
// box decode and sort-key build. Writes keys + proposals directly.
// ---------------------------------------------------------------------------
__global__ __launch_bounds__(256) void k_heads(const float* __restrict__ feat,
                                               const float* __restrict__ w_cls,
                                               const float* __restrict__ b_cls,
                                               const float* __restrict__ w_box,
                                               const float* __restrict__ b_box,
                                               U64* __restrict__ keys,
                                               float4* __restrict__ proposals) {
    __shared__ float red[3][64][45];
    int t = threadIdx.x;
    int px = t & 63, cq = t >> 6;
    int p = blockIdx.x * 64 + px;
    const float* fr = feat + (size_t)p * 512 + cq * 128;
    float acc[45];
#pragma unroll
    for (int o = 0; o < 45; ++o) acc[o] = 0.f;
    for (int c = 0; c < 128; c += 4) {
        float4 f = *(const float4*)(fr + c);
#pragma unroll
        for (int o = 0; o < 45; ++o) {
            const float* wr = ((o < 9) ? (w_cls + o * 512) : (w_box + (o - 9) * 512)) + cq * 128 + c;
            acc[o] += f.x * wr[0] + f.y * wr[1] + f.z * wr[2] + f.w * wr[3];
        }
    }
    if (cq > 0) {
#pragma unroll
        for (int o = 0; o < 45; ++o) red[cq - 1][px][o] = acc[o];
    }
    __syncthreads();
    if (cq == 0) {
#pragma unroll
        for (int o = 0; o < 45; ++o) acc[o] += red[0][px][o] + red[1][px][o] + red[2][px][o];
        int b = p >> 12, pixloc = p & 4095;
        int h = pixloc >> 6, w = pixloc & 63;
        int ibase = b * 36864 + pixloc * 9;
#pragma unroll
        for (int a = 0; a < 9; ++a) {
            float logit = acc[a] + b_cls[a];
            float s = 1.f / (1.f + expf(-logit));
            keys[ibase + a] = (((U64)(__float_as_uint(s) ^ 0x80000000u)) << 32) |
                              (unsigned)(~(unsigned)(pixloc * 9 + a));
            float dx = acc[9 + a * 4 + 0] + b_box[a * 4 + 0];
            float dy = acc[9 + a * 4 + 1] + b_box[a * 4 + 1];
            float dw = fminf(acc[9 + a * 4 + 2] + b_box[a * 4 + 2], 4.135166556742356f);
            float dh = fminf(acc[9 + a * 4 + 3] + b_box[a * 4 + 3], 4.135166556742356f);
            float wa = 2.f * g_bw[a], ha = 2.f * g_bh[a];
            float cx = dx * wa + (float)(w * 16);
            float cy = dy * ha + (float)(h * 16);
            float pw = expf(dw) * wa;
            float ph = expf(dh) * ha;
            proposals[ibase + a] =
                make_float4(cx - 0.5f * pw, cy - 0.5f * ph, cx + 0.5f * pw, cy + 0.5f * ph);
        }
    }
}

// ---------------------------------------------------------------------------
// Sort: 18 chunk-sorts of 2048 (36864 = 18*2048) + merge-4 tree (3 launches).
// ---------------------------------------------------------------------------
__device__ inline void cmp_stage(U64* s, int j, int k, int tid) {
    for (int p = tid; p < 1024; p += 256) {
        int il = ((p & ~(j - 1)) << 1) | (p & (j - 1));
        int ip = il | j;
        U64 a = s[il], c = s[ip];
        bool desc = ((il & k) == 0);
        bool sw = desc ? (a < c) : (a > c);
        if (sw) { s[il] = c; s[ip] = a; }
    }
}

__global__ __launch_bounds__(256) void k_sort_chunk(const U64* __restrict__ keys,
                                                    U64* __restrict__ run) {
    __shared__ U64 s[2048];
    int b = blockIdx.x / 18, ch = blockIdx.x % 18;
    int tid = threadIdx.x;
    const U64* src = keys + (size_t)b * 36864 + ch * 2048;
    for (int e = tid; e < 2048; e += 256) s[e] = src[e];
    __syncthreads();
    for (int k = 2; k <= 2048; k <<= 1)
        for (int j = k >> 1; j >= 1; j >>= 1) {
            cmp_stage(s, j, k, tid);
            __syncthreads();
        }
    U64* dst = run + ((size_t)b * 18 + ch) * 2048;
    for (int e = tid; e < 2048; e += 256) dst[e] = s[e];
}

// merge up to 4 sorted-desc 2048-runs (group g = runs 4g..4g+3) -> top-2048 desc
__global__ __launch_bounds__(256) void k_merge4(const U64* __restrict__ in,
                                                U64* __restrict__ out, int nc) {
    __shared__ U64 s[4096];
    int g = blockIdx.x, b = blockIdx.y;
    int tid = threadIdx.x;
    int r0 = g * 4;
    int n = nc - r0; if (n > 4) n = 4;
    const U64* base = in + (size_t)b * 18 * 2048;
    U64* O = out + ((size_t)b * 18 + g) * 2048;
    for (int e = tid; e < 2048; e += 256) s[e] = base[(size_t)r0 * 2048 + e];
    for (int m = 1; m < n; ++m) {
        for (int e = tid; e < 2048; e += 256) s[4095 - e] = base[(size_t)(r0 + m) * 2048 + e];
        __syncthreads();
        // half-cleaner: keep the 2048 largest in the low half
        for (int e = tid; e < 2048; e += 256) {
            U64 a = s[e], c = s[e + 2048];
            s[e] = (a >= c) ? a : c;
        }
        __syncthreads();
        // bitonic merge of the (bitonic) low half, descending
        for (int j = 1024; j >= 1; j >>= 1) {
            for (int p = tid; p < 1024; p += 256) {
                int il = ((p & ~(j - 1)) << 1) | (p & (j - 1));
                int ip = il | j;
                U64 a = s[il], c = s[ip];
                if (a < c) { s[il] = c; s[ip] = a; }
            }
            __syncthreads();
        }
    }
    for (int e = tid; e < 2048; e += 256) O[e] = s[e];
}

// ---------------------------------------------------------------------------
// K_topk_gather: top-2000/batch from final run, clip, min-size filter.
// ---------------------------------------------------------------------------
__global__ __launch_bounds__(256) void k_topk_gather(const U64* __restrict__ runf,
                                                     const float4* __restrict__ proposals,
                                                     float4* __restrict__ tb_boxes,
                                                     float* __restrict__ tb_scores) {
    int g = blockIdx.x * 256 + threadIdx.x;
    if (g >= 8000) return;
    int b = g / 2000, r = g - b * 2000;
    U64 key = runf[(size_t)b * 18 * 2048 + r];
    unsigned n = ~((unsigned)key);
    float s = __uint_as_float(((unsigned)(key >> 32)) ^ 0x80000000u);
    float4 p = proposals[b * 36864 + (int)n];
    float x1 = fminf(fmaxf(p.x, 0.f), 1024.f);
    float y1 = fminf(fmaxf(p.y, 0.f), 1024.f);
    float x2 = fminf(fmaxf(p.z, 0.f), 1024.f);
    float y2 = fminf(fmaxf(p.w, 0.f), 1024.f);
    bool small_ = ((x2 - x1) < 16.f) || ((y2 - y1) < 16.f);
    tb_boxes[g] = make_float4(x1, y1, x2, y2);
    tb_scores[g] = small_ ? -INFINITY : s;
}

// ---------------------------------------------------------------------------
// K_nms_mask: suppression bitmask. mask[b][i][jt] bit jj = (j>i && iou>0.7).
// ---------------------------------------------------------------------------
__global__ __launch_bounds__(64) void k_nms_mask(const float4* __restrict__ tb_boxes,
                                                 U64* __restrict__ mask) {
    int jt = blockIdx.x, it = blockIdx.y, b = blockIdx.z;
    int tid = threadIdx.x;
    __shared__ float4 jb[64];
    int j0 = jt * 64;
    {
        int j = j0 + tid;
        jb[tid] = (j < 2000) ? tb_boxes[b * 2000 + j] : make_float4(0.f, 0.f, 0.f, 0.f);
    }
    __syncthreads();
    int i = it * 64 + tid;
    if (i >= 2000) return;
    float4 bi = tb_boxes[b * 2000 + i];
    float ai = (bi.z - bi.x) * (bi.w - bi.y);
    U64 bits = 0;
#pragma unroll 4
    for (int jj = 0; jj < 64; ++jj) {
        int j = j0 + jj;
        float4 bj = jb[jj];
        float aj = (bj.z - bj.x) * (bj.w - bj.y);
        float ltx = fmaxf(bi.x, bj.x), lty = fmaxf(bi.y, bj.y);
        float rbx = fminf(bi.z, bj.z), rby = fminf(bi.w, bj.w);
        float ww = fmaxf(rbx - ltx, 0.f), hh2 = fmaxf(rby - lty, 0.f);
        float inter = ww * hh2;
        float iou = inter / (ai + aj - inter);
        if ((j > i) && (j < 2000) && (iou > 0.7f)) bits |= (1ull << jj);
    }
    mask[((size_t)b * 2000 + i) * 32 + jt] = bits;
}

// ---------------------------------------------------------------------------
// K_nms_scan: sequential NMS scan (1 wave/batch) + final top-300 output.
// ---------------------------------------------------------------------------
__global__ __launch_bounds__(64) void k_nms_scan(const float4* __restrict__ tb_boxes,
                                                 const float* __restrict__ tb_scores,
                                                 const U64* __restrict__ mask,
                                                 float* __restrict__ out) {
    int b = blockIdx.x;
    int lane = threadIdx.x;
    __shared__ U64 mbuf[2][2048];
    __shared__ unsigned short keeplist[2000];
    __shared__ unsigned char keepflag[2000];
    __shared__ unsigned short fillq[304];

    U64 remv = 0;
    if (lane < 32) {
        for (int jj = 0; jj < 64; ++jj) {
            int j = (lane << 6) | jj;
            if (j < 2000 && tb_scores[b * 2000 + j] == -INFINITY) remv |= (1ull << jj);
        }
    }
    const U64* mb = mask + (size_t)b * 2000 * 32;
#pragma unroll
    for (int q = 0; q < 32; ++q) {
        int e = q * 64 + lane;
        mbuf[0][e] = mb[(e >> 5) * 32 + (e & 31)];
    }
    __syncthreads();

    int nkeep = 0;
    for (int ch = 0; ch < 32; ++ch) {
        int cur = ch & 1;
        U64 v[32];
        if (ch < 31) {
#pragma unroll
            for (int q = 0; q < 32; ++q) {
                int e = q * 64 + lane;
                int row = (ch + 1) * 64 + (e >> 5), wd = e & 31;
                v[q] = (row < 2000) ? mb[(size_t)row * 32 + wd] : 0ull;
            }
        }
        int iend = min(64, 2000 - ch * 64);
        U64 w_all = __shfl(remv, ch);
        for (int ii = 0; ii < iend; ++ii) {
            bool sup = (w_all >> ii) & 1ull;
            int i = ch * 64 + ii;
            if (!sup) {
                if (lane == 0) keeplist[nkeep] = (unsigned short)i;
                U64 mrow = mbuf[cur][(ii << 5) | (lane & 31)];
                if (lane < 32) remv |= mrow;
                w_all |= mbuf[cur][(ii << 5) | ch];
                nkeep++;
            }
            if (lane == 0) keepflag[i] = sup ? (unsigned char)0 : (unsigned char)1;
        }
        if (ch < 31) {
#pragma unroll
            for (int q = 0; q < 32; ++q) mbuf[cur ^ 1][q * 64 + lane] = v[q];
        }
        __syncthreads();
    }

    if (lane == 0) {
        int need = 300 - nkeep, c = 0;
        for (int i = 0; i < 2000 && c < need; ++i)
            if (!keepflag[i]) fillq[c++] = (unsigned short)i;
    }
    __syncthreads();
    for (int r = lane; r < 300; r += 64) {
        int src; float sc;
        if (r < nkeep) { src = keeplist[r]; sc = tb_scores[b * 2000 + src]; }
        else           { src = fillq[r - nkeep]; sc = -INFINITY; }
        float4 bx = tb_boxes[b * 2000 + src];
        int ob = (b * 300 + r) * 4;
        out[ob + 0] = bx.x; out[ob + 1] = bx.y; out[ob + 2] = bx.z; out[ob + 3] = bx.w;
        out[4800 + b * 300 + r] = sc;
    }
}

// ---------------------------------------------------------------------------
extern "C" void kernel_launch(void* const* d_in, const int* in_sizes, int n_in,
                              void* d_out, int out_size, void* d_ws, size_t ws_size,
                              hipStream_t stream) {
    (void)in_sizes; (void)n_in; (void)out_size; (void)ws_size;
    const float* feature_map = (const float*)d_in[1];
    const float* w_conv = (const float*)d_in[2];
    const float* b_conv = (const float*)d_in[3];
    const float* w_cls  = (const float*)d_in[4];
    const float* b_cls  = (const float*)d_in[5];
    const float* w_box  = (const float*)d_in[6];
    const float* b_box  = (const float*)d_in[7];
    float* out = (float*)d_out;

    char* ws = (char*)d_ws;
    size_t off = 0;
    auto alloc = [&](size_t bytes) {
        void* p = ws + off;
        off = (off + bytes + 255) & ~(size_t)255;
        return p;
    };
    const size_t fpi_elems = 4ull * 66 * 66 * 1024;            // 17.8M f16
    _Float16* fpi = (_Float16*)alloc(fpi_elems * 2);           // 35.7 MB
    _Float16* wki = (_Float16*)alloc(512ull * 9216 * 2);       // 9.4 MB
    float*  feat      = (float*) alloc(16384ull * 512 * 4);    // 33.6 MB
    float4* proposals = (float4*)alloc(4ull * 36864 * 16);     // 2.4 MB
    U64*    keys      = (U64*)   alloc(4ull * 36864 * 8);      // 1.2 MB
    U64*    run0      = (U64*)   alloc(4ull * 18 * 2048 * 8);  // 1.2 MB
    U64*    run1      = (U64*)   alloc(4ull * 18 * 2048 * 8);  // 1.2 MB
    float4* tb_boxes  = (float4*)alloc(8000ull * 16);
    float*  tb_scores = (float*) alloc(8000ull * 4);
    U64*    nmsmask   = (U64*)   alloc(8000ull * 32 * 8);      // 2.0 MB

    hipMemsetAsync(fpi, 0, fpi_elems * 2, stream);
    k_prep_fm<<<dim3(8, 64, 4), 256, 0, stream>>>(feature_map, fpi);
    k_prep_w<<<512, 256, 0, stream>>>(w_conv, wki);
    k_conv_mfma<<<dim3(128, 4), 256, 0, stream>>>(fpi, wki, b_conv, feat);
    k_heads<<<256, 256, 0, stream>>>(feat, w_cls, b_cls, w_box, b_box, keys, proposals);

    k_sort_chunk<<<72, 256, 0, stream>>>(keys, run0);
    k_merge4<<<dim3(5, 4), 256, 0, stream>>>(run0, run1, 18);
    k_merge4<<<dim3(2, 4), 256, 0, stream>>>(run1, run0, 5);
    k_merge4<<<dim3(1, 4), 256, 0, stream>>>(run0, run1, 2);

    k_topk_gather<<<32, 256, 0, stream>>>(run1, proposals, tb_boxes, tb_scores);
    k_nms_mask<<<dim3(32, 32, 4), 64, 0, stream>>>(tb_boxes, nmsmask);
    k_nms_scan<<<4, 64, 0, stream>>>(tb_boxes, tb_scores, nmsmask, out);
}

// Round 6
// 760.310 us; speedup vs baseline: 2.6324x; 1.0349x over previous
//
#include <hip/hip_runtime.h>
#include <math.h>

typedef unsigned long long U64;
typedef _Float16 half8 __attribute__((ext_vector_type(8)));
typedef float f32x16 __attribute__((ext_vector_type(16)));

__device__ const float g_bw[9] = {91.f, 181.f, 362.f, 64.f, 128.f, 256.f, 45.f, 91.f, 181.f};
__device__ const float g_bh[9] = {45.f, 91.f, 181.f, 64.f, 128.f, 256.f, 91.f, 181.f, 362.f};

__device__ inline f32x16 zero16() {
    f32x16 z;
#pragma unroll
    for (int i = 0; i < 16; ++i) z[i] = 0.f;
    return z;
}

#define GLOAD16(G, L)                                                  \
    __builtin_amdgcn_global_load_lds(                                  \
        (const __attribute__((address_space(1))) void*)(G),            \
        (__attribute__((address_space(3))) void*)(L), 16, 0, 0)

// ---------------------------------------------------------------------------
// K_prep_fm: fm NCHW f32 -> padded interleaved f16 planes
// fpi[b][hp 0..65][wp 0..65][chunk 0..15][64] ; chunk inner = [hi x32 | lo x32]
// bid < 512: interior transpose blocks (cg = bid&7, h = bid>>3).
// bid >= 512: halo cell zeroing (replaces the 35.7 MB memset).
// ---------------------------------------------------------------------------
__global__ __launch_bounds__(256) void k_prep_fm(const float* __restrict__ fm,
                                                 _Float16* __restrict__ fpi) {
    int bid = blockIdx.x, b = blockIdx.y;
    int t = threadIdx.x;
    if (bid >= 512) {  // halo: 260 cells per batch
        int ci = bid - 512;
        int hp, wp;
        if (ci < 66)       { hp = 0;  wp = ci; }
        else if (ci < 132) { hp = 65; wp = ci - 66; }
        else { int k = ci - 132; hp = 1 + (k & 63); wp = (k < 64) ? 0 : 65; }
        uint2 z; z.x = 0u; z.y = 0u;
        *(uint2*)(fpi + ((size_t)(b * 66 + hp) * 66 + wp) * 1024 + t * 4) = z;
        return;
    }
    __shared__ float tile[64][65];
    int cg = bid & 7, h = bid >> 3;
    int cl = t >> 2, w0 = (t & 3) * 16;
    const float* src = fm + (((size_t)(b * 512 + cg * 64 + cl) * 64 + h) * 64 + w0);
#pragma unroll
    for (int l = 0; l < 4; ++l) {
        float4 v = *(const float4*)(src + l * 4);
        tile[cl][w0 + l * 4 + 0] = v.x; tile[cl][w0 + l * 4 + 1] = v.y;
        tile[cl][w0 + l * 4 + 2] = v.z; tile[cl][w0 + l * 4 + 3] = v.w;
    }
    __syncthreads();
    int w = t & 63, pth = t >> 6;
    int chunkrel = pth >> 1, half = pth & 1;
    _Float16* dst = fpi + ((size_t)((b * 66 + h + 1) * 66) + (w + 1)) * 1024 +
                    (cg * 2 + chunkrel) * 64 + half * 32;
#pragma unroll
    for (int g8 = 0; g8 < 4; ++g8) {
        half8 v;
#pragma unroll
        for (int i = 0; i < 8; ++i) {
            float x = tile[chunkrel * 32 + g8 * 8 + i][w];
            _Float16 hi = (_Float16)x;
            v[i] = half ? (_Float16)((x - (float)hi) * 2048.0f) : hi;
        }
        *(half8*)(dst + g8 * 8) = v;
    }
}

// ---------------------------------------------------------------------------
// K_prep_w: w_conv [512 o][512 c][9 tap] f32 -> wki[o][chunk=tap*16+cg][64]
// chunk inner = [hi x32 | lo x32] f16. One block per o.
// ---------------------------------------------------------------------------
__global__ __launch_bounds__(256) void k_prep_w(const float* __restrict__ w_conv,
                                                _Float16* __restrict__ wki) {
    __shared__ float wb[4608];
    int o = blockIdx.x, t = threadIdx.x;
    for (int e = t; e < 4608; e += 256) wb[e] = w_conv[(size_t)o * 4608 + e];
    __syncthreads();
    for (int e = t; e < 9216; e += 256) {
        int s = e & 63, chunk = e >> 6;
        int tap = chunk >> 4, cgi = chunk & 15;
        int c = cgi * 32 + (s & 31);
        float x = wb[c * 9 + tap];
        _Float16 hi = (_Float16)x;
        wki[(size_t)o * 9216 + e] = (s < 32) ? hi : (_Float16)((x - (float)hi) * 2048.0f);
    }
}

// ---------------------------------------------------------------------------
// K_conv_mfma: implicit-GEMM 3x3 conv via mfma_f32_32x32x16_f16, hi/lo split.
// Round-6: SGB-pinned phase interleave [DS12][MFMA6][DS4][MFMA18] + setprio
// around MFMA clusters. Sync skeleton (vmcnt(8)+barriers+DMA) unchanged.
// ---------------------------------------------------------------------------
__global__ __launch_bounds__(256, 2) void k_conv_mfma(
    const _Float16* __restrict__ fpi, const _Float16* __restrict__ wki,
    const float* __restrict__ bconv, float* __restrict__ feat) {
    __shared__ _Float16 As[2][128][64];
    __shared__ _Float16 Bs[2][128][64];
    const int t = threadIdx.x;
    const int lane = t & 63, wv = t >> 6;
    const int wm = wv >> 1, wn = wv & 1;
    int flat = (int)blockIdx.x + 128 * (int)blockIdx.y;
    int fid = (flat & 7) * 64 + (flat >> 3);
    const int p0 = (fid >> 2) * 128, o0 = (fid & 3) * 128;

    const char* baseA[4];
    const char* baseB[4];
#pragma unroll
    for (int q = 0; q < 4; ++q) {
        int row = wv * 32 + q * 8 + (lane >> 3);
        int qs = (lane & 7) ^ (row & 7);
        int P = p0 + row;
        int bb = P >> 12, hh = (P >> 6) & 63, ww = P & 63;
        baseA[q] = (const char*)fpi + ((size_t)((bb * 66 + hh) * 66 + ww)) * 2048 + qs * 16;
        baseB[q] = (const char*)wki + (size_t)(o0 + row) * 18432 + qs * 16;
    }

    f32x16 acc0[2][2], acc1[2][2];
#pragma unroll
    for (int mi = 0; mi < 2; ++mi)
#pragma unroll
        for (int ni = 0; ni < 2; ++ni) { acc0[mi][ni] = zero16(); acc1[mi][ni] = zero16(); }

    auto issue = [&](int it2, int buf) {
        int tap = it2 >> 4;
        int ry = (tap * 11) >> 5, rx = tap - ry * 3;
        int ka = (ry * 66 + rx) * 2048 + (it2 & 15) * 128;
        int kb = it2 * 128;
#pragma unroll
        for (int q = 0; q < 4; ++q) {
            GLOAD16(baseA[q] + ka, &As[buf][wv * 32 + q * 8][0]);
            GLOAD16(baseB[q] + kb, &Bs[buf][wv * 32 + q * 8][0]);
        }
    };

    issue(0, 0);
    issue(1, 1);

#define LOADA(mi_)                                                              \
    {                                                                           \
        int rA = wm * 64 + (mi_) * 32 + (lane & 31);                            \
        int xa = (rA & 7) << 4, ba = rA * 128;                                  \
        af[mi_][0][0] = *(const half8*)(ab + ba + ((0 + lg) ^ xa));             \
        af[mi_][0][1] = *(const half8*)(ab + ba + ((32 + lg) ^ xa));            \
        af[mi_][1][0] = *(const half8*)(ab + ba + ((64 + lg) ^ xa));            \
        af[mi_][1][1] = *(const half8*)(ab + ba + ((96 + lg) ^ xa));            \
    }
#define LOADB(ni_)                                                              \
    {                                                                           \
        int rB = wn * 64 + (ni_) * 32 + (lane & 31);                            \
        int xb = (rB & 7) << 4, bb0 = rB * 128;                                 \
        bf[ni_][0][0] = *(const half8*)(bb2 + bb0 + ((0 + lg) ^ xb));           \
        bf[ni_][0][1] = *(const half8*)(bb2 + bb0 + ((32 + lg) ^ xb));          \
        bf[ni_][1][0] = *(const half8*)(bb2 + bb0 + ((64 + lg) ^ xb));          \
        bf[ni_][1][1] = *(const half8*)(bb2 + bb0 + ((96 + lg) ^ xb));          \
    }
#define QUAD(mi_, ni_)                                                                                     \
    acc0[mi_][ni_] = __builtin_amdgcn_mfma_f32_32x32x16_f16(af[mi_][0][0], bf[ni_][0][0], acc0[mi_][ni_], 0, 0, 0); \
    acc0[mi_][ni_] = __builtin_amdgcn_mfma_f32_32x32x16_f16(af[mi_][0][1], bf[ni_][0][1], acc0[mi_][ni_], 0, 0, 0); \
    acc1[mi_][ni_] = __builtin_amdgcn_mfma_f32_32x32x16_f16(af[mi_][0][0], bf[ni_][1][0], acc1[mi_][ni_], 0, 0, 0); \
    acc1[mi_][ni_] = __builtin_amdgcn_mfma_f32_32x32x16_f16(af[mi_][0][1], bf[ni_][1][1], acc1[mi_][ni_], 0, 0, 0); \
    acc1[mi_][ni_] = __builtin_amdgcn_mfma_f32_32x32x16_f16(af[mi_][1][0], bf[ni_][0][0], acc1[mi_][ni_], 0, 0, 0); \
    acc1[mi_][ni_] = __builtin_amdgcn_mfma_f32_32x32x16_f16(af[mi_][1][1], bf[ni_][0][1], acc1[mi_][ni_], 0, 0, 0);

    for (int it = 0; it < 144; ++it) {
        int cur = it & 1;
        if (it < 143) { asm volatile("s_waitcnt vmcnt(8)" ::: "memory"); }
        else          { asm volatile("s_waitcnt vmcnt(0)" ::: "memory"); }
        __builtin_amdgcn_s_barrier();
        __builtin_amdgcn_sched_barrier(0);

        const char* ab = (const char*)As + cur * 16384;
        const char* bb2 = (const char*)Bs + cur * 16384;
        const int lg = (lane >> 5) * 16;
        half8 af[2][2][2], bf[2][2][2];

        LOADA(0) LOADB(0) LOADA(1)            // 12 ds_read_b128
        __builtin_amdgcn_s_setprio(1);
        QUAD(0, 0)                            // 6 MFMA
        __builtin_amdgcn_s_setprio(0);
        LOADB(1)                              // 4 ds_read_b128
        __builtin_amdgcn_s_setprio(1);
        QUAD(1, 0) QUAD(0, 1) QUAD(1, 1)      // 18 MFMA
        __builtin_amdgcn_s_setprio(0);

        __builtin_amdgcn_sched_group_barrier(0x100, 12, 0);  // DS_READ x12
        __builtin_amdgcn_sched_group_barrier(0x008, 6, 0);   // MFMA x6
        __builtin_amdgcn_sched_group_barrier(0x100, 4, 0);   // DS_READ x4
        __builtin_amdgcn_sched_group_barrier(0x008, 18, 0);  // MFMA x18

        __builtin_amdgcn_sched_barrier(0);
        __builtin_amdgcn_s_barrier();
        __builtin_amdgcn_sched_barrier(0);
        if (it < 142) issue(it + 2, cur);
    }

    // epilogue: combine + bias + relu; C/D map col=lane&31, row=(q&3)+8*(q>>2)+4*(lane>>5)
#pragma unroll
    for (int mi = 0; mi < 2; ++mi)
#pragma unroll
        for (int ni = 0; ni < 2; ++ni) {
            int col = o0 + wn * 64 + ni * 32 + (lane & 31);
            float bv = bconv[col];
            int rbase = p0 + wm * 64 + mi * 32 + 4 * (lane >> 5);
#pragma unroll
            for (int q = 0; q < 16; ++q) {
                int row = rbase + (q & 3) + 8 * (q >> 2);
                float v = acc0[mi][ni][q] + acc1[mi][ni][q] * 4.8828125e-4f + bv;
                feat[(size_t)row * 512 + col] = fmaxf(v, 0.f);
            }
        }
}

// ---------------------------------------------------------------------------
// K_heads: 1x1 heads (4-way channel split + LDS reduce) fused with sigmoid,
// box decode and sort-key build.
// ---------------------------------------------------------------------------
__global__ __launch_bounds__(256) void k_heads(const float* __restrict__ feat,
                                               const float* __restrict__ w_cls,
                                               const float* __restrict__ b_cls,
                                               const float* __restrict__ w_box,
                                               const float* __restrict__ b_box,
                                               U64* __restrict__ keys,
                                               float4* __restrict__ proposals) {
    __shared__ float red[3][64][45];
    int t = threadIdx.x;
    int px = t & 63, cq = t >> 6;
    int p = blockIdx.x * 64 + px;
    const float* fr = feat + (size_t)p * 512 + cq * 128;
    float acc[45];
#pragma unroll
    for (int o = 0; o < 45; ++o) acc[o] = 0.f;
    for (int c = 0; c < 128; c += 4) {
        float4 f = *(const float4*)(fr + c);
#pragma unroll
        for (int o = 0; o < 45; ++o) {
            const float* wr = ((o < 9) ? (w_cls + o * 512) : (w_box + (o - 9) * 512)) + cq * 128 + c;
            acc[o] += f.x * wr[0] + f.y * wr[1] + f.z * wr[2] + f.w * wr[3];
        }
    }
    if (cq > 0) {
#pragma unroll
        for (int o = 0; o < 45; ++o) red[cq - 1][px][o] = acc[o];
    }
    __syncthreads();
    if (cq == 0) {
#pragma unroll
        for (int o = 0; o < 45; ++o) acc[o] += red[0][px][o] + red[1][px][o] + red[2][px][o];
        int b = p >> 12, pixloc = p & 4095;
        int h = pixloc >> 6, w = pixloc & 63;
        int ibase = b * 36864 + pixloc * 9;
#pragma unroll
        for (int a = 0; a < 9; ++a) {
            float logit = acc[a] + b_cls[a];
            float s = 1.f / (1.f + expf(-logit));
            keys[ibase + a] = (((U64)(__float_as_uint(s) ^ 0x80000000u)) << 32) |
                              (unsigned)(~(unsigned)(pixloc * 9 + a));
            float dx = acc[9 + a * 4 + 0] + b_box[a * 4 + 0];
            float dy = acc[9 + a * 4 + 1] + b_box[a * 4 + 1];
            float dw = fminf(acc[9 + a * 4 + 2] + b_box[a * 4 + 2], 4.135166556742356f);
            float dh = fminf(acc[9 + a * 4 + 3] + b_box[a * 4 + 3], 4.135166556742356f);
            float wa = 2.f * g_bw[a], ha = 2.f * g_bh[a];
            float cx = dx * wa + (float)(w * 16);
            float cy = dy * ha + (float)(h * 16);
            float pw = expf(dw) * wa;
            float ph = expf(dh) * ha;
            proposals[ibase + a] =
                make_float4(cx - 0.5f * pw, cy - 0.5f * ph, cx + 0.5f * pw, cy + 0.5f * ph);
        }
    }
}

// ---------------------------------------------------------------------------
// Sort: 18 chunk-sorts of 2048 (36864 = 18*2048) + merge-4 tree (3 launches).
// ---------------------------------------------------------------------------
__device__ inline void cmp_stage(U64* s, int j, int k, int tid) {
    for (int p = tid; p < 1024; p += 256) {
        int il = ((p & ~(j - 1)) << 1) | (p & (j - 1));
        int ip = il | j;
        U64 a = s[il], c = s[ip];
        bool desc = ((il & k) == 0);
        bool sw = desc ? (a < c) : (a > c);
        if (sw) { s[il] = c; s[ip] = a; }
    }
}

__global__ __launch_bounds__(256) void k_sort_chunk(const U64* __restrict__ keys,
                                                    U64* __restrict__ run) {
    __shared__ U64 s[2048];
    int b = blockIdx.x / 18, ch = blockIdx.x % 18;
    int tid = threadIdx.x;
    const U64* src = keys + (size_t)b * 36864 + ch * 2048;
    for (int e = tid; e < 2048; e += 256) s[e] = src[e];
    __syncthreads();
    for (int k = 2; k <= 2048; k <<= 1)
        for (int j = k >> 1; j >= 1; j >>= 1) {
            cmp_stage(s, j, k, tid);
            __syncthreads();
        }
    U64* dst = run + ((size_t)b * 18 + ch) * 2048;
    for (int e = tid; e < 2048; e += 256) dst[e] = s[e];
}

// merge up to 4 sorted-desc 2048-runs (group g = runs 4g..4g+3) -> top-2048 desc
__global__ __launch_bounds__(256) void k_merge4(const U64* __restrict__ in,
                                                U64* __restrict__ out, int nc) {
    __shared__ U64 s[4096];
    int g = blockIdx.x, b = blockIdx.y;
    int tid = threadIdx.x;
    int r0 = g * 4;
    int n = nc - r0; if (n > 4) n = 4;
    const U64* base = in + (size_t)b * 18 * 2048;
    U64* O = out + ((size_t)b * 18 + g) * 2048;
    for (int e = tid; e < 2048; e += 256) s[e] = base[(size_t)r0 * 2048 + e];
    for (int m = 1; m < n; ++m) {
        for (int e = tid; e < 2048; e += 256) s[4095 - e] = base[(size_t)(r0 + m) * 2048 + e];
        __syncthreads();
        for (int e = tid; e < 2048; e += 256) {
            U64 a = s[e], c = s[e + 2048];
            s[e] = (a >= c) ? a : c;
        }
        __syncthreads();
        for (int j = 1024; j >= 1; j >>= 1) {
            for (int p = tid; p < 1024; p += 256) {
                int il = ((p & ~(j - 1)) << 1) | (p & (j - 1));
                int ip = il | j;
                U64 a = s[il], c = s[ip];
                if (a < c) { s[il] = c; s[ip] = a; }
            }
            __syncthreads();
        }
    }
    for (int e = tid; e < 2048; e += 256) O[e] = s[e];
}

// ---------------------------------------------------------------------------
// K_topk_gather: top-2000/batch from final run, clip, min-size filter.
// ---------------------------------------------------------------------------
__global__ __launch_bounds__(256) void k_topk_gather(const U64* __restrict__ runf,
                                                     const float4* __restrict__ proposals,
                                                     float4* __restrict__ tb_boxes,
                                                     float* __restrict__ tb_scores) {
    int g = blockIdx.x * 256 + threadIdx.x;
    if (g >= 8000) return;
    int b = g / 2000, r = g - b * 2000;
    U64 key = runf[(size_t)b * 18 * 2048 + r];
    unsigned n = ~((unsigned)key);
    float s = __uint_as_float(((unsigned)(key >> 32)) ^ 0x80000000u);
    float4 p = proposals[b * 36864 + (int)n];
    float x1 = fminf(fmaxf(p.x, 0.f), 1024.f);
    float y1 = fminf(fmaxf(p.y, 0.f), 1024.f);
    float x2 = fminf(fmaxf(p.z, 0.f), 1024.f);
    float y2 = fminf(fmaxf(p.w, 0.f), 1024.f);
    bool small_ = ((x2 - x1) < 16.f) || ((y2 - y1) < 16.f);
    tb_boxes[g] = make_float4(x1, y1, x2, y2);
    tb_scores[g] = small_ ? -INFINITY : s;
}

// ---------------------------------------------------------------------------
// K_nms_mask: suppression bitmask. mask[b][i][jt] bit jj = (j>i && iou>0.7).
// ---------------------------------------------------------------------------
__global__ __launch_bounds__(64) void k_nms_mask(const float4* __restrict__ tb_boxes,
                                                 U64* __restrict__ mask) {
    int jt = blockIdx.x, it = blockIdx.y, b = blockIdx.z;
    int tid = threadIdx.x;
    __shared__ float4 jb[64];
    int j0 = jt * 64;
    {
        int j = j0 + tid;
        jb[tid] = (j < 2000) ? tb_boxes[b * 2000 + j] : make_float4(0.f, 0.f, 0.f, 0.f);
    }
    __syncthreads();
    int i = it * 64 + tid;
    if (i >= 2000) return;
    float4 bi = tb_boxes[b * 2000 + i];
    float ai = (bi.z - bi.x) * (bi.w - bi.y);
    U64 bits = 0;
#pragma unroll 4
    for (int jj = 0; jj < 64; ++jj) {
        int j = j0 + jj;
        float4 bj = jb[jj];
        float aj = (bj.z - bj.x) * (bj.w - bj.y);
        float ltx = fmaxf(bi.x, bj.x), lty = fmaxf(bi.y, bj.y);
        float rbx = fminf(bi.z, bj.z), rby = fminf(bi.w, bj.w);
        float ww = fmaxf(rbx - ltx, 0.f), hh2 = fmaxf(rby - lty, 0.f);
        float inter = ww * hh2;
        float iou = inter / (ai + aj - inter);
        if ((j > i) && (j < 2000) && (iou > 0.7f)) bits |= (1ull << jj);
    }
    mask[((size_t)b * 2000 + i) * 32 + jt] = bits;
}

// ---------------------------------------------------------------------------
// K_nms_scan: sequential NMS scan (1 wave/batch), mask chunks in REGISTERS
// (ping-pong cva/cvb, fully unrolled static indexing). Serial chain per kept
// box is now one shfl (~10 cy) instead of an LDS read (~120 cy).
// Layout: cv[q] lane l = word (l&31) of chunk-row q*2+(l>>5).
// ---------------------------------------------------------------------------
__global__ __launch_bounds__(64) void k_nms_scan(const float4* __restrict__ tb_boxes,
                                                 const float* __restrict__ tb_scores,
                                                 const U64* __restrict__ mask,
                                                 float* __restrict__ out) {
    int b = blockIdx.x;
    int lane = threadIdx.x;
    __shared__ unsigned short keeplist[2000];
    __shared__ unsigned char keepflag[2000];
    __shared__ unsigned short fillq[304];

    U64 remv = 0;
    if (lane < 32) {
        for (int jj = 0; jj < 64; ++jj) {
            int j = (lane << 6) | jj;
            if (j < 2000 && tb_scores[b * 2000 + j] == -INFINITY) remv |= (1ull << jj);
        }
    }
    const U64* mb = mask + (size_t)b * 2000 * 32;

    U64 cva[32], cvb[32];
    int nkeep = 0;

    auto loadchunk = [&](U64 (&cv)[32], int ch) {
#pragma unroll
        for (int q = 0; q < 32; ++q) {
            int row = ch * 64 + q * 2 + (lane >> 5), wd = lane & 31;
            cv[q] = (row < 2000) ? mb[(size_t)row * 32 + wd] : 0ull;
        }
    };
    auto process = [&](U64 (&cv)[32], int ch) {
        int base = ch * 64;
        int iend = (2000 - base < 64) ? (2000 - base) : 64;
        U64 w_all = __shfl(remv, ch);
#pragma unroll
        for (int ii = 0; ii < 64; ++ii) {
            if (ii < iend) {
                bool sup = (w_all >> ii) & 1ull;
                int i = base + ii;
                if (!sup) {
                    if (lane == 0) keeplist[nkeep] = (unsigned short)i;
                    U64 mrow = __shfl(cv[ii >> 1], ((ii & 1) << 5) | (lane & 31));
                    if (lane < 32) remv |= mrow;
                    w_all |= __shfl(cv[ii >> 1], ((ii & 1) << 5) | ch);
                    nkeep++;
                }
                if (lane == 0) keepflag[i] = sup ? (unsigned char)0 : (unsigned char)1;
            }
        }
    };

    loadchunk(cva, 0);
    for (int ch2 = 0; ch2 < 32; ch2 += 2) {
        loadchunk(cvb, ch2 + 1);
        process(cva, ch2);
        if (ch2 + 2 < 32) loadchunk(cva, ch2 + 2);
        process(cvb, ch2 + 1);
    }
    __syncthreads();

    if (lane == 0) {
        int need = 300 - nkeep, c = 0;
        for (int i = 0; i < 2000 && c < need; ++i)
            if (!keepflag[i]) fillq[c++] = (unsigned short)i;
    }
    __syncthreads();
    for (int r = lane; r < 300; r += 64) {
        int src; float sc;
        if (r < nkeep) { src = keeplist[r]; sc = tb_scores[b * 2000 + src]; }
        else           { src = fillq[r - nkeep]; sc = -INFINITY; }
        float4 bx = tb_boxes[b * 2000 + src];
        int ob = (b * 300 + r) * 4;
        out[ob + 0] = bx.x; out[ob + 1] = bx.y; out[ob + 2] = bx.z; out[ob + 3] = bx.w;
        out[4800 + b * 300 + r] = sc;
    }
}

// ---------------------------------------------------------------------------
extern "C" void kernel_launch(void* const* d_in, const int* in_sizes, int n_in,
                              void* d_out, int out_size, void* d_ws, size_t ws_size,
                              hipStream_t stream) {
    (void)in_sizes; (void)n_in; (void)out_size; (void)ws_size;
    const float* feature_map = (const float*)d_in[1];
    const float* w_conv = (const float*)d_in[2];
    const float* b_conv = (const float*)d_in[3];
    const float* w_cls  = (const float*)d_in[4];
    const float* b_cls  = (const float*)d_in[5];
    const float* w_box  = (const float*)d_in[6];
    const float* b_box  = (const float*)d_in[7];
    float* out = (float*)d_out;

    char* ws = (char*)d_ws;
    size_t off = 0;
    auto alloc = [&](size_t bytes) {
        void* p = ws + off;
        off = (off + bytes + 255) & ~(size_t)255;
        return p;
    };
    const size_t fpi_elems = 4ull * 66 * 66 * 1024;            // 17.8M f16
    _Float16* fpi = (_Float16*)alloc(fpi_elems * 2);           // 35.7 MB
    _Float16* wki = (_Float16*)alloc(512ull * 9216 * 2);       // 9.4 MB
    float*  feat      = (float*) alloc(16384ull * 512 * 4);    // 33.6 MB
    float4* proposals = (float4*)alloc(4ull * 36864 * 16);     // 2.4 MB
    U64*    keys      = (U64*)   alloc(4ull * 36864 * 8);      // 1.2 MB
    U64*    run0      = (U64*)   alloc(4ull * 18 * 2048 * 8);  // 1.2 MB
    U64*    run1      = (U64*)   alloc(4ull * 18 * 2048 * 8);  // 1.2 MB
    float4* tb_boxes  = (float4*)alloc(8000ull * 16);
    float*  tb_scores = (float*) alloc(8000ull * 4);
    U64*    nmsmask   = (U64*)   alloc(8000ull * 32 * 8);      // 2.0 MB

    k_prep_fm<<<dim3(772, 4), 256, 0, stream>>>(feature_map, fpi);
    k_prep_w<<<512, 256, 0, stream>>>(w_conv, wki);
    k_conv_mfma<<<dim3(128, 4), 256, 0, stream>>>(fpi, wki, b_conv, feat);
    k_heads<<<256, 256, 0, stream>>>(feat, w_cls, b_cls, w_box, b_box, keys, proposals);

    k_sort_chunk<<<72, 256, 0, stream>>>(keys, run0);
    k_merge4<<<dim3(5, 4), 256, 0, stream>>>(run0, run1, 18);
    k_merge4<<<dim3(2, 4), 256, 0, stream>>>(run1, run0, 5);
    k_merge4<<<dim3(1, 4), 256, 0, stream>>>(run0, run1, 2);

    k_topk_gather<<<32, 256, 0, stream>>>(run1, proposals, tb_boxes, tb_scores);
    k_nms_mask<<<dim3(32, 32, 4), 64, 0, stream>>>(tb_boxes, nmsmask);
    k_nms_scan<<<4, 64, 0, stream>>>(tb_boxes, tb_scores, nmsmask, out);
}